// Round 8
// baseline (248.414 us; speedup 1.0000x reference)
//
#include <hip/hip_runtime.h>

typedef _Float16 f16;
typedef _Float16 half8 __attribute__((ext_vector_type(8)));
typedef float floatx4 __attribute__((ext_vector_type(4)));

#define MFMA16(a,b,c) __builtin_amdgcn_mfma_f32_16x16x32_f16((a),(b),(c),0,0,0)
// (1/sqrt(128)) * log2(e)
#define RSL2E 0.12751743f

__device__ __forceinline__ void split2(float x, f16 &h, f16 &l) {
  f16 hh = (f16)x;
  h = hh;
  l = (f16)(x - (float)hh);
}

// ---- LDS staging: rows of 64 halves (128B pitch), XOR-swizzled ----
__device__ __forceinline__ void stage_rows64(const f16* __restrict__ g, int gstride,
                                             f16* lds, int rows, int tid, int nthr) {
  int total = rows * 8;
  for (int idx = tid; idx < total; idx += nthr) {
    int row = idx >> 3, slot = idx & 7;
    float4 v = *(const float4*)(g + (size_t)row * gstride + slot * 8);
    int lofs = ((row << 7) + (slot << 4)) ^ ((row & 7) << 4);
    *(float4*)((char*)lds + lofs) = v;
  }
}
// rows of 128 halves (256B pitch), XOR-swizzled
__device__ __forceinline__ void stage_rows128(const f16* __restrict__ g, int gstride,
                                              f16* lds, int rows, int tid, int nthr) {
  int total = rows * 16;
  for (int idx = tid; idx < total; idx += nthr) {
    int row = idx >> 4, slot = idx & 15;
    float4 v = *(const float4*)(g + (size_t)row * gstride + slot * 8);
    int lofs = ((row << 8) + (slot << 4)) ^ ((row & 7) << 4);
    *(float4*)((char*)lds + lofs) = v;
  }
}
// stage fp32 rows with on-the-fly split into h/l tiles (64 cols, 128B pitch each)
__device__ __forceinline__ void stage_split64(const float* __restrict__ g, int gstride,
                                              f16* ldsh, f16* ldsl, int rows,
                                              int tid, int nthr) {
  int total = rows * 16;
  for (int idx = tid; idx < total; idx += nthr) {
    int row = idx >> 4, cg = idx & 15;
    float4 va = *(const float4*)(g + (size_t)row * gstride + cg * 4);
    union { f16 a[4]; uint2 u; } hh, ll;
    split2(va.x, hh.a[0], ll.a[0]);
    split2(va.y, hh.a[1], ll.a[1]);
    split2(va.z, hh.a[2], ll.a[2]);
    split2(va.w, hh.a[3], ll.a[3]);
    int lofs = ((row << 7) + (cg << 3)) ^ ((row & 7) << 4);
    *(uint2*)((char*)ldsh + lofs) = hh.u;
    *(uint2*)((char*)ldsl + lofs) = ll.u;
  }
}
__device__ __forceinline__ half8 fragP128(const f16* lds, int row, int kofs) {
  int ofs = ((row << 7) + (kofs << 1)) ^ ((row & 7) << 4);
  return *(const half8*)((const char*)lds + ofs);
}
__device__ __forceinline__ half8 fragP256(const f16* lds, int row, int kofs) {
  int ofs = ((row << 8) + (kofs << 1)) ^ ((row & 7) << 4);
  return *(const half8*)((const char*)lds + ofs);
}

// ---- transpose + split the three weight matrices ----
__global__ void k_splitW(const float* __restrict__ Wq, const float* __restrict__ Wkv,
                         const float* __restrict__ Wo,
                         f16* WqTh, f16* WqTl, f16* WkvTh, f16* WkvTl,
                         f16* WoTh, f16* WoTl) {
  int idx = blockIdx.x * 256 + threadIdx.x;
  if (idx >= 65536) return;
  float v; f16 *ph, *pl; int dst;
  if (idx < 16384) {
    int n = idx >> 7, c = idx & 127;
    v = Wq[c * 128 + n]; ph = WqTh; pl = WqTl; dst = idx;
  } else if (idx < 49152) {
    int t = idx - 16384; int n = t >> 7, c = t & 127;
    v = Wkv[c * 256 + n]; ph = WkvTh; pl = WkvTl; dst = t;
  } else {
    int t = idx - 49152; int n = t >> 7, c = t & 127;
    v = Wo[c * 128 + n]; ph = WoTh; pl = WoTl; dst = t;
  }
  f16 h, l; split2(v, h, l);
  ph[dst] = h; pl[dst] = l;
}

// ---- fused split+GEMM: out[64 rows][128 cols] = split(A_f32) * BT^T + bias ----
// Output SINGLE f16. mode 0: row-major [l][c]; mode 1: transposed vT [b][c][l]
__global__ __launch_bounds__(512, 2)
void k_proj(const float* __restrict__ A,
            const f16* __restrict__ BTh, const f16* __restrict__ BTl,
            const float* __restrict__ bias,
            f16* __restrict__ out, int mode) {
  __shared__ f16 pool[24576];
  f16* sAh = pool;           // [64][64]
  f16* sAl = pool + 4096;
  f16* sBh = pool + 8192;    // [128][64]
  f16* sBl = pool + 16384;
  int tid = threadIdx.x, wave = tid >> 6, lane = tid & 63, lg = lane >> 4, lr = lane & 15;
  int wm = wave >> 2, wn = wave & 3;   // 2 x 4 waves, 32x32 wave tiles
  size_t rowbase = (size_t)blockIdx.x * 64;
  floatx4 zero = {0.f, 0.f, 0.f, 0.f};
  floatx4 acc[2][2] = {{zero, zero}, {zero, zero}};
  for (int cc = 0; cc < 128; cc += 64) {
    __syncthreads();
    stage_split64(A + rowbase * 128 + cc, 128, sAh, sAl, 64, tid, 512);
    stage_rows64(BTh + cc, 128, sBh, 128, tid, 512);
    stage_rows64(BTl + cc, 128, sBl, 128, tid, 512);
    __syncthreads();
    for (int kc = 0; kc < 64; kc += 32) {
      half8 ah[2], al[2];
      for (int fm = 0; fm < 2; fm++) {
        ah[fm] = fragP128(sAh, wm * 32 + fm * 16 + lr, kc + lg * 8);
        al[fm] = fragP128(sAl, wm * 32 + fm * 16 + lr, kc + lg * 8);
      }
      for (int fn = 0; fn < 2; fn++) {
        half8 bh = fragP128(sBh, wn * 32 + fn * 16 + lr, kc + lg * 8);
        half8 bl = fragP128(sBl, wn * 32 + fn * 16 + lr, kc + lg * 8);
        for (int fm = 0; fm < 2; fm++) {
          acc[fm][fn] = MFMA16(ah[fm], bh, acc[fm][fn]);
          acc[fm][fn] = MFMA16(ah[fm], bl, acc[fm][fn]);
          acc[fm][fn] = MFMA16(al[fm], bh, acc[fm][fn]);
        }
      }
    }
  }
  __syncthreads();
  f16* e = pool;          // [64][136] padded, single
  for (int fm = 0; fm < 2; fm++) for (int fn = 0; fn < 2; fn++) {
    int n = wn * 32 + fn * 16 + lr;
    float bs = bias[n];
    for (int jj = 0; jj < 4; jj++) {
      int m = wm * 32 + fm * 16 + lg * 4 + jj;
      e[m * 136 + n] = (f16)(acc[fm][fn][jj] + bs);
    }
  }
  __syncthreads();
  if (mode == 0) {
    for (int idx = tid; idx < 1024; idx += 512) {
      int r = idx >> 4, sl = idx & 15;
      *(float4*)(out + (rowbase + r) * 128 + sl * 8) =
          *(const float4*)((const char*)e + r * 272 + sl * 16);
    }
  } else {
    size_t bidx = rowbase >> 13, lofs = rowbase & 8191;
    for (int idx = tid; idx < 1024; idx += 512) {
      int c = idx >> 3, sl = idx & 7;
      union { f16 a[8]; float4 v; } th;
      for (int t = 0; t < 8; t++) th.a[t] = e[(sl * 8 + t) * 136 + c];
      *(float4*)(out + (bidx * 128 + c) * 8192 + lofs + sl * 8) = th.v;
    }
  }
}

// ---- fused reduce+final projection: out fp32 = (Pbuf0+Pbuf1+U) * WoT^T + bo ----
__global__ __launch_bounds__(512, 2)
void k_final(const float* __restrict__ Pbuf, const float* __restrict__ U,
             const f16* __restrict__ BTh, const f16* __restrict__ BTl,
             const float* __restrict__ bias, float* __restrict__ out) {
  __shared__ f16 pool[24576];
  f16* sAh = pool;
  f16* sAl = pool + 4096;
  f16* sBh = pool + 8192;
  f16* sBl = pool + 16384;
  int tid = threadIdx.x, wave = tid >> 6, lane = tid & 63, lg = lane >> 4, lr = lane & 15;
  int wm = wave >> 2, wn = wave & 3;
  size_t rowbase = (size_t)blockIdx.x * 64;
  // map rows -> (b,i,st) -> Pbuf tile
  int b = (int)(rowbase >> 13), r0 = (int)(rowbase & 8191);
  int i = r0 >> 9, st = (r0 >> 6) & 7;
  const float* p0 = Pbuf + ((size_t)((((b * 16 + i) * 8 + st) * 2) + 0)) * 8192;
  const float* p1 = p0 + 8192;
  const float* Ub = U + ((size_t)b * 16 + i) * 128;
  floatx4 zero = {0.f, 0.f, 0.f, 0.f};
  floatx4 acc[2][2] = {{zero, zero}, {zero, zero}};
  for (int cc = 0; cc < 128; cc += 64) {
    __syncthreads();
    // A-stage: sum partials + U, split into h/l
    for (int idx = tid; idx < 1024; idx += 512) {
      int row = idx >> 4, cg = idx & 15;
      int c = cc + cg * 4;
      float4 a0 = *(const float4*)(p0 + row * 128 + c);
      float4 a1 = *(const float4*)(p1 + row * 128 + c);
      float4 uu = *(const float4*)(Ub + c);
      float vals[4] = {a0.x + a1.x + uu.x, a0.y + a1.y + uu.y,
                       a0.z + a1.z + uu.z, a0.w + a1.w + uu.w};
      union { f16 a[4]; uint2 u; } hh, ll;
      for (int t = 0; t < 4; t++) split2(vals[t], hh.a[t], ll.a[t]);
      int lofs = ((row << 7) + (cg << 3)) ^ ((row & 7) << 4);
      *(uint2*)((char*)sAh + lofs) = hh.u;
      *(uint2*)((char*)sAl + lofs) = ll.u;
    }
    stage_rows64(BTh + cc, 128, sBh, 128, tid, 512);
    stage_rows64(BTl + cc, 128, sBl, 128, tid, 512);
    __syncthreads();
    for (int kc = 0; kc < 64; kc += 32) {
      half8 ah[2], al[2];
      for (int fm = 0; fm < 2; fm++) {
        ah[fm] = fragP128(sAh, wm * 32 + fm * 16 + lr, kc + lg * 8);
        al[fm] = fragP128(sAl, wm * 32 + fm * 16 + lr, kc + lg * 8);
      }
      for (int fn = 0; fn < 2; fn++) {
        half8 bh = fragP128(sBh, wn * 32 + fn * 16 + lr, kc + lg * 8);
        half8 bl = fragP128(sBl, wn * 32 + fn * 16 + lr, kc + lg * 8);
        for (int fm = 0; fm < 2; fm++) {
          acc[fm][fn] = MFMA16(ah[fm], bh, acc[fm][fn]);
          acc[fm][fn] = MFMA16(ah[fm], bl, acc[fm][fn]);
          acc[fm][fn] = MFMA16(al[fm], bh, acc[fm][fn]);
        }
      }
    }
  }
  __syncthreads();
  float* ef = (float*)pool;   // [64][132] padded fp32
  for (int fm = 0; fm < 2; fm++) for (int fn = 0; fn < 2; fn++) {
    int n = wn * 32 + fn * 16 + lr;
    float bs = bias[n];
    for (int jj = 0; jj < 4; jj++) {
      int m = wm * 32 + fm * 16 + lg * 4 + jj;
      ef[m * 132 + n] = acc[fm][fn][jj] + bs;
    }
  }
  __syncthreads();
  for (int idx = tid; idx < 2048; idx += 512) {
    int r = idx >> 5, sl = idx & 31;
    *(float4*)(out + (rowbase + r) * 128 + sl * 4) = *(const float4*)(ef + r * 132 + sl * 4);
  }
}

// ---- U[b][i][c] = (1/512) * sum over disallowed k-blocks of their column sums of v ----
__global__ void k_U(const f16* __restrict__ vT, float* __restrict__ U) {
  int b = blockIdx.x >> 7, c = blockIdx.x & 127;
  int tid = threadIdx.x;
  const f16* r = vT + ((size_t)b * 128 + c) * 8192;
  float s = 0.f;
  const float4* r4 = (const float4*)(r + tid * 32);
  for (int t = 0; t < 4; t++) {
    float4 v = r4[t];
    const f16* a = (const f16*)&v;
    for (int u = 0; u < 8; u++) s += (float)a[u];
  }
  __shared__ float part[256];
  __shared__ float bs[16];
  part[tid] = s;
  __syncthreads();
  if (tid < 16) {
    float t = 0.f;
    for (int u = 0; u < 16; u++) t += part[tid * 16 + u];
    bs[tid] = t;
  }
  __syncthreads();
  if (tid < 16) {
    int i = tid;
    float tot = 0.f;
    for (int j = 0; j < 16; j++) tot += bs[j];
    int j0 = i - 2 < 0 ? 0 : i - 2;
    int j1 = i + 2 > 15 ? 15 : i + 2;
    float win = 0.f;
    for (int j = j0; j <= j1; j++) win += bs[j];
    U[((size_t)b * 16 + i) * 128 + c] = (tot - win) * (1.0f / 512.0f);
  }
}

// ---- pass A: Z[b][i][j][d] = sum_s exp2(RSL2E * (k_d . q_s)), single f16 inputs ----
__global__ __launch_bounds__(512, 4)
void k_passA(const f16* __restrict__ kp, const f16* __restrict__ qp,
             float* __restrict__ Z) {
  int bid = blockIdx.x;
  int wg = (bid & 7) * 80 + (bid >> 3);     // XCD-aware bijective swizzle (640 = 8*80)
  int dchunk = wg & 3; int rest = wg >> 2;
  int slot = rest % 5; int rest2 = rest / 5;
  int i = rest2 & 15; int b = rest2 >> 4;
  int j = i - 2 + slot;
  if (j < 0 || j > 15) return;
  __shared__ f16 sK[16384], sQ[16384];  // 64 KiB -> 2 WG/CU
  int tid = threadIdx.x, wave = tid >> 6, lane = tid & 63, lg = lane >> 4, lr = lane & 15;
  int wm = wave >> 1, wn = wave & 1;   // 4 x 2 waves; wave tile 32(d) x 64(s)
  size_t krow = (size_t)b * 8192 + j * 512 + dchunk * 128;
  stage_rows128(kp + krow * 128, 128, sK, 128, tid, 512);
  float zp[2][4] = {{0.f,0.f,0.f,0.f},{0.f,0.f,0.f,0.f}};
  floatx4 zero = {0.f, 0.f, 0.f, 0.f};
  for (int sc = 0; sc < 4; sc++) {
    __syncthreads();
    size_t qrow = (size_t)b * 8192 + i * 512 + sc * 128;
    stage_rows128(qp + qrow * 128, 128, sQ, 128, tid, 512);
    __syncthreads();
    floatx4 acc[2][4] = {{zero,zero,zero,zero},{zero,zero,zero,zero}};
    for (int kc = 0; kc < 128; kc += 32) {
      half8 ah[2];
      for (int fm = 0; fm < 2; fm++)
        ah[fm] = fragP256(sK, wm * 32 + fm * 16 + lr, kc + lg * 8);
      for (int fn = 0; fn < 4; fn++) {
        half8 bh = fragP256(sQ, wn * 64 + fn * 16 + lr, kc + lg * 8);
        for (int fm = 0; fm < 2; fm++)
          acc[fm][fn] = MFMA16(ah[fm], bh, acc[fm][fn]);
      }
    }
    for (int fm = 0; fm < 2; fm++) for (int fn = 0; fn < 4; fn++)
      for (int jj = 0; jj < 4; jj++)
        zp[fm][jj] += exp2f(acc[fm][fn][jj] * RSL2E);
  }
  // in-wave butterfly over lr (16 s-columns)
  for (int off = 1; off < 16; off <<= 1)
    for (int fm = 0; fm < 2; fm++) for (int jj = 0; jj < 4; jj++)
      zp[fm][jj] += __shfl_xor(zp[fm][jj], off, 64);
  // cross-wave combine of the two wn halves via LDS
  __syncthreads();
  float* sred = (float*)sQ;      // 256 floats
  if (lr == 0) {
    for (int fm = 0; fm < 2; fm++) for (int jj = 0; jj < 4; jj++) {
      int d = wm * 32 + fm * 16 + lg * 4 + jj;
      sred[wn * 128 + d] = zp[fm][jj];
    }
  }
  __syncthreads();
  if (tid < 128) {
    size_t zb = (((size_t)(b * 16 + i) * 16 + j) * 512) + dchunk * 128;
    Z[zb + tid] = sred[tid] + sred[128 + tid];
  }
}

// ---- pass B (R5 structure + register prefetch of K / V / Z) ----
// per (b, i, s-tile 64, d-half): partial PV into Pbuf (f32); 40 KB LDS
__global__ __launch_bounds__(512, 4)
void k_passB(const f16* __restrict__ qp, const f16* __restrict__ kp,
             const f16* __restrict__ vT,
             const float* __restrict__ Z, float* __restrict__ Pbuf) {
  int bid = blockIdx.x;
  int wg = ((bid & 7) << 6) | (bid >> 3);   // XCD-aware bijective swizzle (512 = 8*64)
  int dhalf = wg & 1, st = (wg >> 1) & 7, i = (wg >> 4) & 15, b = wg >> 8;
  __shared__ __align__(16) char pool[40960];
  f16* sQ  = (f16*)pool;             // [64 s][128 c], 256B pitch, 16 KB
  f16* sKV = (f16*)(pool + 16384);   // [128][64], 128B pitch, 16 KB (K halves / vT tiles)
  f16* sE  = (f16*)(pool + 32768);   // [64 s][64 d], 128B pitch, 8 KB
  int tid = threadIdx.x, wave = tid >> 6, lane = tid & 63, lg = lane >> 4, lr = lane & 15;
  int w1m = wave >> 1, w1n = wave & 1;    // GEMM1: 4(d) x 2(s)
  int w2m = wave >> 2, w2n = wave & 3;    // GEMM2: 2(s) x 4(c)
  // K-stage duty (rows krr, krr+64; 16B slot ksl)
  int krr = tid >> 3, ksl = tid & 7;
  int lofsA = ((krr << 7) + (ksl << 4)) ^ ((krr & 7) << 4);
  int lofsB = (((krr + 64) << 7) + (ksl << 4)) ^ ((krr & 7) << 4);
  // V-stage duty (4 rows per thread among 256 stager threads)
  int vr0 = (tid >> 3) & 31, vsl = tid & 7;
  int vlofs[4];
  #pragma unroll
  for (int t = 0; t < 4; t++)
    vlofs[t] = (((vr0 + t * 32) << 7) + (vsl << 4)) ^ ((vr0 & 7) << 4);
  size_t qrow = (size_t)b * 8192 + i * 512 + st * 64;
  stage_rows128(qp + qrow * 128, 128, sQ, 64, tid, 512);
  floatx4 zero = {0.f, 0.f, 0.f, 0.f};
  floatx4 acc2[2][2] = {{zero, zero}, {zero, zero}};
  int j0 = i - 2 < 0 ? 0 : i - 2, j1 = i + 2 > 15 ? 15 : i + 2;
  const f16* vbase = vT + (size_t)b * 1048576;
  // prefetch K for first iteration
  const f16* kb0 = kp + ((size_t)b * 8192 + j0 * 512 + (dhalf * 2) * 128) * 128;
  float4 k0a = *(const float4*)(kb0 + krr * 128 + ksl * 8);
  float4 k0b = *(const float4*)(kb0 + (krr + 64) * 128 + ksl * 8);
  float4 k1a = *(const float4*)(kb0 + krr * 128 + 64 + ksl * 8);
  float4 k1b = *(const float4*)(kb0 + (krr + 64) * 128 + 64 + ksl * 8);
  for (int j = j0; j <= j1; j++) {
    #pragma unroll
    for (int dc = 0; dc < 2; dc++) {
      int dchunk = dhalf * 2 + dc;
      // Z reciprocals prefetched at iter start
      float rz[2][4];
      {
        size_t zb = (((size_t)(b * 16 + i) * 16 + j) * 512) + dchunk * 128;
        #pragma unroll
        for (int fm = 0; fm < 2; fm++)
          #pragma unroll
          for (int jj = 0; jj < 4; jj++)
            rz[fm][jj] = 1.0f / Z[zb + w1m * 32 + fm * 16 + lg * 4 + jj];
      }
      // V(dsub0) prefetch by its stager waves (4..7)
      float4 v0[4], v1[4];
      if (wave >= 4) {
        const f16* gv = vbase + (size_t)j * 512 + dchunk * 128;
        #pragma unroll
        for (int t = 0; t < 4; t++)
          v0[t] = *(const float4*)(gv + (size_t)(vr0 + t * 32) * 8192 + vsl * 8);
      }
      __syncthreads();                      // prev GEMM2-dsub1 done with sKV/sE
      *(float4*)((char*)sKV + lofsA) = k0a;
      *(float4*)((char*)sKV + lofsB) = k0b;
      __syncthreads();
      // GEMM1a (cc = 0..63)
      floatx4 acc1[2][2] = {{zero, zero}, {zero, zero}};
      #pragma unroll
      for (int kc = 0; kc < 64; kc += 32) {
        half8 ah0 = fragP128(sKV, w1m * 32 + lr, kc + lg * 8);
        half8 ah1 = fragP128(sKV, w1m * 32 + 16 + lr, kc + lg * 8);
        #pragma unroll
        for (int fn = 0; fn < 2; fn++) {
          half8 bq = fragP256(sQ, w1n * 32 + fn * 16 + lr, kc + lg * 8);
          acc1[0][fn] = MFMA16(ah0, bq, acc1[0][fn]);
          acc1[1][fn] = MFMA16(ah1, bq, acc1[1][fn]);
        }
      }
      __syncthreads();
      *(float4*)((char*)sKV + lofsA) = k1a;
      *(float4*)((char*)sKV + lofsB) = k1b;
      // prefetch next iteration's K (a full iteration to land)
      {
        int nj = j, ndc = dc + 1;
        if (ndc == 2) { ndc = 0; nj = j + 1; }
        if (nj <= j1) {
          const f16* nkb = kp + ((size_t)b * 8192 + nj * 512 + (dhalf * 2 + ndc) * 128) * 128;
          k0a = *(const float4*)(nkb + krr * 128 + ksl * 8);
          k0b = *(const float4*)(nkb + (krr + 64) * 128 + ksl * 8);
          k1a = *(const float4*)(nkb + krr * 128 + 64 + ksl * 8);
          k1b = *(const float4*)(nkb + (krr + 64) * 128 + 64 + ksl * 8);
        }
      }
      __syncthreads();
      // GEMM1b (cc = 64..127)
      #pragma unroll
      for (int kc = 0; kc < 64; kc += 32) {
        half8 ah0 = fragP128(sKV, w1m * 32 + lr, kc + lg * 8);
        half8 ah1 = fragP128(sKV, w1m * 32 + 16 + lr, kc + lg * 8);
        #pragma unroll
        for (int fn = 0; fn < 2; fn++) {
          half8 bq = fragP256(sQ, w1n * 32 + fn * 16 + lr, 64 + kc + lg * 8);
          acc1[0][fn] = MFMA16(ah0, bq, acc1[0][fn]);
          acc1[1][fn] = MFMA16(ah1, bq, acc1[1][fn]);
        }
      }
      #pragma unroll
      for (int dsub = 0; dsub < 2; dsub++) {
        __syncthreads();   // prev readers of sE / sKV done
        if ((w1m >> 1) == dsub) {
          // writer waves: E' = exp(S)/Z (single f16)
          #pragma unroll
          for (int fm = 0; fm < 2; fm++)
            #pragma unroll
            for (int fn = 0; fn < 2; fn++)
              #pragma unroll
              for (int jj = 0; jj < 4; jj++) {
                int dl = w1m * 32 + fm * 16 + lg * 4 + jj;
                int ds = dl - dsub * 64;
                int s = w1n * 32 + fn * 16 + lr;
                float e = exp2f(acc1[fm][fn][jj] * RSL2E) * rz[fm][jj];
                int ofs = ((s << 7) + (ds << 1)) ^ ((s & 7) << 4);
                *(f16*)((char*)sE + ofs) = (f16)e;
              }
        } else {
          // stager waves: write prefetched V tile
          #pragma unroll
          for (int t = 0; t < 4; t++)
            *(float4*)((char*)sKV + vlofs[t]) = (dsub == 0) ? v0[t] : v1[t];
        }
        if (dsub == 0 && wave < 4) {
          // prefetch V(dsub1) by its stager waves (0..3) after their E-write
          const f16* gv = vbase + (size_t)j * 512 + dchunk * 128 + 64;
          #pragma unroll
          for (int t = 0; t < 4; t++)
            v1[t] = *(const float4*)(gv + (size_t)(vr0 + t * 32) * 8192 + vsl * 8);
        }
        __syncthreads();
        #pragma unroll
        for (int kc = 0; kc < 64; kc += 32) {
          half8 ea0 = fragP128(sE, w2m * 32 + lr, kc + lg * 8);
          half8 ea1 = fragP128(sE, w2m * 32 + 16 + lr, kc + lg * 8);
          #pragma unroll
          for (int fn = 0; fn < 2; fn++) {
            half8 bh = fragP128(sKV, w2n * 32 + fn * 16 + lr, kc + lg * 8);
            acc2[0][fn] = MFMA16(ea0, bh, acc2[0][fn]);
            acc2[1][fn] = MFMA16(ea1, bh, acc2[1][fn]);
          }
        }
      }
    }
  }
  // epilogue: write f32 partial to Pbuf via LDS for coalescing
  __syncthreads();
  float* ef = (float*)pool;   // [64][128] f32 = 32 KB (overlays sQ+sKV)
  #pragma unroll
  for (int fm = 0; fm < 2; fm++)
    #pragma unroll
    for (int fn = 0; fn < 2; fn++) {
      int c = w2n * 32 + fn * 16 + lr;
      #pragma unroll
      for (int jj = 0; jj < 4; jj++) {
        int s = w2m * 32 + fm * 16 + lg * 4 + jj;
        ef[s * 128 + c] = acc2[fm][fn][jj];
      }
    }
  __syncthreads();
  float* po = Pbuf + ((size_t)((((b * 16 + i) * 8 + st) * 2) + dhalf)) * 8192;
  for (int idx = tid; idx < 2048; idx += 512)
    ((float4*)po)[idx] = ((const float4*)ef)[idx];
}

extern "C" void kernel_launch(void* const* d_in, const int* in_sizes, int n_in,
                              void* d_out, int out_size, void* d_ws, size_t ws_size,
                              hipStream_t stream) {
  const float* query     = (const float*)d_in[0];
  const float* key_value = (const float*)d_in[1];
  const float* Wq  = (const float*)d_in[2];
  const float* bq  = (const float*)d_in[3];
  const float* Wkv = (const float*)d_in[4];
  const float* bkv = (const float*)d_in[5];
  const float* Wo  = (const float*)d_in[6];
  const float* bo  = (const float*)d_in[7];
  float* out = (float*)d_out;

  char* ws = (char*)d_ws;
  size_t off = 0;
  auto alloc = [&](size_t bytes) -> char* {
    char* p = ws + off;
    off += (bytes + 255) & ~(size_t)255;
    return p;
  };
  const size_t SZH = (size_t)16384 * 128 * 2;   // one f16 array over all rows
  f16* qhp  = (f16*)alloc(SZH);   // q projected, single f16
  f16* khp  = (f16*)alloc(SZH);   // k projected, single f16
  f16* vT   = (f16*)alloc(SZH);   // v projected, transposed [b][c][l], single f16
  float* Pbuf = (float*)alloc((size_t)512 * 8192 * 4);   // 16.78 MB partials
  f16* WqTh  = (f16*)alloc(32768); f16* WqTl  = (f16*)alloc(32768);
  f16* WkvTh = (f16*)alloc(65536); f16* WkvTl = (f16*)alloc(65536);
  f16* WoTh  = (f16*)alloc(32768); f16* WoTl  = (f16*)alloc(32768);
  float* Zb = (float*)alloc((size_t)2 * 16 * 16 * 512 * 4);
  float* Ub = (float*)alloc((size_t)2 * 16 * 128 * 4);
  if (off > ws_size) return;   // workspace too small: bail

  k_splitW<<<256, 256, 0, stream>>>(Wq, Wkv, Wo, WqTh, WqTl, WkvTh, WkvTl, WoTh, WoTl);
  // q projection (fused fp32 split)
  k_proj<<<256, 512, 0, stream>>>(query, WqTh, WqTl, bq, qhp, 0);
  // k projection (first 128 channels of Wkv)
  k_proj<<<256, 512, 0, stream>>>(key_value, WkvTh, WkvTl, bkv, khp, 0);
  // v projection (second 128 channels), stored transposed [b][c][l]
  k_proj<<<256, 512, 0, stream>>>(key_value, WkvTh + 128 * 128, WkvTl + 128 * 128,
                                  bkv + 128, vT, 1);
  k_U<<<256, 256, 0, stream>>>(vT, Ub);
  k_passA<<<640, 512, 0, stream>>>(khp, qhp, Zb);
  k_passB<<<512, 512, 0, stream>>>(qhp, khp, vT, Zb, Pbuf);
  k_final<<<256, 512, 0, stream>>>(Pbuf, Ub, WoTh, WoTl, bo, out);
}

// Round 9
// 134.211 us; speedup vs baseline: 1.8509x; 1.8509x over previous
//
#include <hip/hip_runtime.h>

typedef _Float16 f16;
typedef _Float16 half8 __attribute__((ext_vector_type(8)));
typedef float floatx4 __attribute__((ext_vector_type(4)));

#define MFMA16(a,b,c) __builtin_amdgcn_mfma_f32_16x16x32_f16((a),(b),(c),0,0,0)
// (1/sqrt(128)) * log2(e)
#define RSL2E 0.12751743f

__device__ __forceinline__ void split2(float x, f16 &h, f16 &l) {
  f16 hh = (f16)x;
  h = hh;
  l = (f16)(x - (float)hh);
}

// ---- LDS staging: rows of 64 halves (128B pitch), XOR-swizzled ----
__device__ __forceinline__ void stage_rows64(const f16* __restrict__ g, int gstride,
                                             f16* lds, int rows, int tid, int nthr) {
  int total = rows * 8;
  for (int idx = tid; idx < total; idx += nthr) {
    int row = idx >> 3, slot = idx & 7;
    float4 v = *(const float4*)(g + (size_t)row * gstride + slot * 8);
    int lofs = ((row << 7) + (slot << 4)) ^ ((row & 7) << 4);
    *(float4*)((char*)lds + lofs) = v;
  }
}
// rows of 128 halves (256B pitch), XOR-swizzled
__device__ __forceinline__ void stage_rows128(const f16* __restrict__ g, int gstride,
                                              f16* lds, int rows, int tid, int nthr) {
  int total = rows * 16;
  for (int idx = tid; idx < total; idx += nthr) {
    int row = idx >> 4, slot = idx & 15;
    float4 v = *(const float4*)(g + (size_t)row * gstride + slot * 8);
    int lofs = ((row << 8) + (slot << 4)) ^ ((row & 7) << 4);
    *(float4*)((char*)lds + lofs) = v;
  }
}
// stage fp32 rows with on-the-fly split into h/l tiles (64 cols, 128B pitch each)
__device__ __forceinline__ void stage_split64(const float* __restrict__ g, int gstride,
                                              f16* ldsh, f16* ldsl, int rows,
                                              int tid, int nthr) {
  int total = rows * 16;
  for (int idx = tid; idx < total; idx += nthr) {
    int row = idx >> 4, cg = idx & 15;
    float4 va = *(const float4*)(g + (size_t)row * gstride + cg * 4);
    union { f16 a[4]; uint2 u; } hh, ll;
    split2(va.x, hh.a[0], ll.a[0]);
    split2(va.y, hh.a[1], ll.a[1]);
    split2(va.z, hh.a[2], ll.a[2]);
    split2(va.w, hh.a[3], ll.a[3]);
    int lofs = ((row << 7) + (cg << 3)) ^ ((row & 7) << 4);
    *(uint2*)((char*)ldsh + lofs) = hh.u;
    *(uint2*)((char*)ldsl + lofs) = ll.u;
  }
}
__device__ __forceinline__ half8 fragP128(const f16* lds, int row, int kofs) {
  int ofs = ((row << 7) + (kofs << 1)) ^ ((row & 7) << 4);
  return *(const half8*)((const char*)lds + ofs);
}
__device__ __forceinline__ half8 fragP256(const f16* lds, int row, int kofs) {
  int ofs = ((row << 8) + (kofs << 1)) ^ ((row & 7) << 4);
  return *(const half8*)((const char*)lds + ofs);
}

// ---- transpose + split the three weight matrices ----
__global__ void k_splitW(const float* __restrict__ Wq, const float* __restrict__ Wkv,
                         const float* __restrict__ Wo,
                         f16* WqTh, f16* WqTl, f16* WkvTh, f16* WkvTl,
                         f16* WoTh, f16* WoTl) {
  int idx = blockIdx.x * 256 + threadIdx.x;
  if (idx >= 65536) return;
  float v; f16 *ph, *pl; int dst;
  if (idx < 16384) {
    int n = idx >> 7, c = idx & 127;
    v = Wq[c * 128 + n]; ph = WqTh; pl = WqTl; dst = idx;
  } else if (idx < 49152) {
    int t = idx - 16384; int n = t >> 7, c = t & 127;
    v = Wkv[c * 256 + n]; ph = WkvTh; pl = WkvTl; dst = t;
  } else {
    int t = idx - 49152; int n = t >> 7, c = t & 127;
    v = Wo[c * 128 + n]; ph = WoTh; pl = WoTl; dst = t;
  }
  f16 h, l; split2(v, h, l);
  ph[dst] = h; pl[dst] = l;
}

// ---- fused split+GEMM: out[64 rows][128 cols] = split(A_f32) * BT^T + bias ----
// Output SINGLE f16. mode 0: row-major [l][c]; mode 1: transposed vT [b][c][l]
__global__ __launch_bounds__(512, 2)
void k_proj(const float* __restrict__ A,
            const f16* __restrict__ BTh, const f16* __restrict__ BTl,
            const float* __restrict__ bias,
            f16* __restrict__ out, int mode) {
  __shared__ f16 pool[24576];
  f16* sAh = pool;           // [64][64]
  f16* sAl = pool + 4096;
  f16* sBh = pool + 8192;    // [128][64]
  f16* sBl = pool + 16384;
  int tid = threadIdx.x, wave = tid >> 6, lane = tid & 63, lg = lane >> 4, lr = lane & 15;
  int wm = wave >> 2, wn = wave & 3;   // 2 x 4 waves, 32x32 wave tiles
  size_t rowbase = (size_t)blockIdx.x * 64;
  floatx4 zero = {0.f, 0.f, 0.f, 0.f};
  floatx4 acc[2][2] = {{zero, zero}, {zero, zero}};
  for (int cc = 0; cc < 128; cc += 64) {
    __syncthreads();
    stage_split64(A + rowbase * 128 + cc, 128, sAh, sAl, 64, tid, 512);
    stage_rows64(BTh + cc, 128, sBh, 128, tid, 512);
    stage_rows64(BTl + cc, 128, sBl, 128, tid, 512);
    __syncthreads();
    for (int kc = 0; kc < 64; kc += 32) {
      half8 ah[2], al[2];
      for (int fm = 0; fm < 2; fm++) {
        ah[fm] = fragP128(sAh, wm * 32 + fm * 16 + lr, kc + lg * 8);
        al[fm] = fragP128(sAl, wm * 32 + fm * 16 + lr, kc + lg * 8);
      }
      for (int fn = 0; fn < 2; fn++) {
        half8 bh = fragP128(sBh, wn * 32 + fn * 16 + lr, kc + lg * 8);
        half8 bl = fragP128(sBl, wn * 32 + fn * 16 + lr, kc + lg * 8);
        for (int fm = 0; fm < 2; fm++) {
          acc[fm][fn] = MFMA16(ah[fm], bh, acc[fm][fn]);
          acc[fm][fn] = MFMA16(ah[fm], bl, acc[fm][fn]);
          acc[fm][fn] = MFMA16(al[fm], bh, acc[fm][fn]);
        }
      }
    }
  }
  __syncthreads();
  f16* e = pool;          // [64][136] padded, single
  for (int fm = 0; fm < 2; fm++) for (int fn = 0; fn < 2; fn++) {
    int n = wn * 32 + fn * 16 + lr;
    float bs = bias[n];
    for (int jj = 0; jj < 4; jj++) {
      int m = wm * 32 + fm * 16 + lg * 4 + jj;
      e[m * 136 + n] = (f16)(acc[fm][fn][jj] + bs);
    }
  }
  __syncthreads();
  if (mode == 0) {
    for (int idx = tid; idx < 1024; idx += 512) {
      int r = idx >> 4, sl = idx & 15;
      *(float4*)(out + (rowbase + r) * 128 + sl * 8) =
          *(const float4*)((const char*)e + r * 272 + sl * 16);
    }
  } else {
    size_t bidx = rowbase >> 13, lofs = rowbase & 8191;
    for (int idx = tid; idx < 1024; idx += 512) {
      int c = idx >> 3, sl = idx & 7;
      union { f16 a[8]; float4 v; } th;
      for (int t = 0; t < 8; t++) th.a[t] = e[(sl * 8 + t) * 136 + c];
      *(float4*)(out + (bidx * 128 + c) * 8192 + lofs + sl * 8) = th.v;
    }
  }
}

// ---- fused reduce+final projection: out fp32 = (Pbuf0+Pbuf1+U) * WoT^T + bo ----
__global__ __launch_bounds__(512, 2)
void k_final(const float* __restrict__ Pbuf, const float* __restrict__ U,
             const f16* __restrict__ BTh, const f16* __restrict__ BTl,
             const float* __restrict__ bias, float* __restrict__ out) {
  __shared__ f16 pool[24576];
  f16* sAh = pool;
  f16* sAl = pool + 4096;
  f16* sBh = pool + 8192;
  f16* sBl = pool + 16384;
  int tid = threadIdx.x, wave = tid >> 6, lane = tid & 63, lg = lane >> 4, lr = lane & 15;
  int wm = wave >> 2, wn = wave & 3;
  size_t rowbase = (size_t)blockIdx.x * 64;
  // map rows -> (b,i,st) -> Pbuf tile
  int b = (int)(rowbase >> 13), r0 = (int)(rowbase & 8191);
  int i = r0 >> 9, st = (r0 >> 6) & 7;
  const float* p0 = Pbuf + ((size_t)((((b * 16 + i) * 8 + st) * 2) + 0)) * 8192;
  const float* p1 = p0 + 8192;
  const float* Ub = U + ((size_t)b * 16 + i) * 128;
  floatx4 zero = {0.f, 0.f, 0.f, 0.f};
  floatx4 acc[2][2] = {{zero, zero}, {zero, zero}};
  for (int cc = 0; cc < 128; cc += 64) {
    __syncthreads();
    // A-stage: sum partials + U, split into h/l
    for (int idx = tid; idx < 1024; idx += 512) {
      int row = idx >> 4, cg = idx & 15;
      int c = cc + cg * 4;
      float4 a0 = *(const float4*)(p0 + row * 128 + c);
      float4 a1 = *(const float4*)(p1 + row * 128 + c);
      float4 uu = *(const float4*)(Ub + c);
      float vals[4] = {a0.x + a1.x + uu.x, a0.y + a1.y + uu.y,
                       a0.z + a1.z + uu.z, a0.w + a1.w + uu.w};
      union { f16 a[4]; uint2 u; } hh, ll;
      for (int t = 0; t < 4; t++) split2(vals[t], hh.a[t], ll.a[t]);
      int lofs = ((row << 7) + (cg << 3)) ^ ((row & 7) << 4);
      *(uint2*)((char*)sAh + lofs) = hh.u;
      *(uint2*)((char*)sAl + lofs) = ll.u;
    }
    stage_rows64(BTh + cc, 128, sBh, 128, tid, 512);
    stage_rows64(BTl + cc, 128, sBl, 128, tid, 512);
    __syncthreads();
    for (int kc = 0; kc < 64; kc += 32) {
      half8 ah[2], al[2];
      for (int fm = 0; fm < 2; fm++) {
        ah[fm] = fragP128(sAh, wm * 32 + fm * 16 + lr, kc + lg * 8);
        al[fm] = fragP128(sAl, wm * 32 + fm * 16 + lr, kc + lg * 8);
      }
      for (int fn = 0; fn < 2; fn++) {
        half8 bh = fragP128(sBh, wn * 32 + fn * 16 + lr, kc + lg * 8);
        half8 bl = fragP128(sBl, wn * 32 + fn * 16 + lr, kc + lg * 8);
        for (int fm = 0; fm < 2; fm++) {
          acc[fm][fn] = MFMA16(ah[fm], bh, acc[fm][fn]);
          acc[fm][fn] = MFMA16(ah[fm], bl, acc[fm][fn]);
          acc[fm][fn] = MFMA16(al[fm], bh, acc[fm][fn]);
        }
      }
    }
  }
  __syncthreads();
  float* ef = (float*)pool;   // [64][132] padded fp32
  for (int fm = 0; fm < 2; fm++) for (int fn = 0; fn < 2; fn++) {
    int n = wn * 32 + fn * 16 + lr;
    float bs = bias[n];
    for (int jj = 0; jj < 4; jj++) {
      int m = wm * 32 + fm * 16 + lg * 4 + jj;
      ef[m * 132 + n] = acc[fm][fn][jj] + bs;
    }
  }
  __syncthreads();
  for (int idx = tid; idx < 2048; idx += 512) {
    int r = idx >> 5, sl = idx & 31;
    *(float4*)(out + (rowbase + r) * 128 + sl * 4) = *(const float4*)(ef + r * 132 + sl * 4);
  }
}

// ---- U[b][i][c] = (1/512) * sum over disallowed k-blocks of their column sums of v ----
__global__ void k_U(const f16* __restrict__ vT, float* __restrict__ U) {
  int b = blockIdx.x >> 7, c = blockIdx.x & 127;
  int tid = threadIdx.x;
  const f16* r = vT + ((size_t)b * 128 + c) * 8192;
  float s = 0.f;
  const float4* r4 = (const float4*)(r + tid * 32);
  for (int t = 0; t < 4; t++) {
    float4 v = r4[t];
    const f16* a = (const f16*)&v;
    for (int u = 0; u < 8; u++) s += (float)a[u];
  }
  __shared__ float part[256];
  __shared__ float bs[16];
  part[tid] = s;
  __syncthreads();
  if (tid < 16) {
    float t = 0.f;
    for (int u = 0; u < 16; u++) t += part[tid * 16 + u];
    bs[tid] = t;
  }
  __syncthreads();
  if (tid < 16) {
    int i = tid;
    float tot = 0.f;
    for (int j = 0; j < 16; j++) tot += bs[j];
    int j0 = i - 2 < 0 ? 0 : i - 2;
    int j1 = i + 2 > 15 ? 15 : i + 2;
    float win = 0.f;
    for (int j = j0; j <= j1; j++) win += bs[j];
    U[((size_t)b * 16 + i) * 128 + c] = (tot - win) * (1.0f / 512.0f);
  }
}

// ---- pass A: Z[b][i][j][d] = sum_s exp2(RSL2E * (k_d . q_s)), single f16 inputs ----
__global__ __launch_bounds__(512, 4)
void k_passA(const f16* __restrict__ kp, const f16* __restrict__ qp,
             float* __restrict__ Z) {
  int bid = blockIdx.x;
  int wg = (bid & 7) * 80 + (bid >> 3);     // XCD-aware bijective swizzle (640 = 8*80)
  int dchunk = wg & 3; int rest = wg >> 2;
  int slot = rest % 5; int rest2 = rest / 5;
  int i = rest2 & 15; int b = rest2 >> 4;
  int j = i - 2 + slot;
  if (j < 0 || j > 15) return;
  __shared__ f16 sK[16384], sQ[16384];  // 64 KiB -> 2 WG/CU
  int tid = threadIdx.x, wave = tid >> 6, lane = tid & 63, lg = lane >> 4, lr = lane & 15;
  int wm = wave >> 1, wn = wave & 1;   // 4 x 2 waves; wave tile 32(d) x 64(s)
  size_t krow = (size_t)b * 8192 + j * 512 + dchunk * 128;
  stage_rows128(kp + krow * 128, 128, sK, 128, tid, 512);
  float zp[2][4] = {{0.f,0.f,0.f,0.f},{0.f,0.f,0.f,0.f}};
  floatx4 zero = {0.f, 0.f, 0.f, 0.f};
  for (int sc = 0; sc < 4; sc++) {
    __syncthreads();
    size_t qrow = (size_t)b * 8192 + i * 512 + sc * 128;
    stage_rows128(qp + qrow * 128, 128, sQ, 128, tid, 512);
    __syncthreads();
    floatx4 acc[2][4] = {{zero,zero,zero,zero},{zero,zero,zero,zero}};
    for (int kc = 0; kc < 128; kc += 32) {
      half8 ah[2];
      for (int fm = 0; fm < 2; fm++)
        ah[fm] = fragP256(sK, wm * 32 + fm * 16 + lr, kc + lg * 8);
      for (int fn = 0; fn < 4; fn++) {
        half8 bh = fragP256(sQ, wn * 64 + fn * 16 + lr, kc + lg * 8);
        for (int fm = 0; fm < 2; fm++)
          acc[fm][fn] = MFMA16(ah[fm], bh, acc[fm][fn]);
      }
    }
    for (int fm = 0; fm < 2; fm++) for (int fn = 0; fn < 4; fn++)
      for (int jj = 0; jj < 4; jj++)
        zp[fm][jj] += exp2f(acc[fm][fn][jj] * RSL2E);
  }
  // in-wave butterfly over lr (16 s-columns)
  for (int off = 1; off < 16; off <<= 1)
    for (int fm = 0; fm < 2; fm++) for (int jj = 0; jj < 4; jj++)
      zp[fm][jj] += __shfl_xor(zp[fm][jj], off, 64);
  // cross-wave combine of the two wn halves via LDS
  __syncthreads();
  float* sred = (float*)sQ;      // 256 floats
  if (lr == 0) {
    for (int fm = 0; fm < 2; fm++) for (int jj = 0; jj < 4; jj++) {
      int d = wm * 32 + fm * 16 + lg * 4 + jj;
      sred[wn * 128 + d] = zp[fm][jj];
    }
  }
  __syncthreads();
  if (tid < 128) {
    size_t zb = (((size_t)(b * 16 + i) * 16 + j) * 512) + dchunk * 128;
    Z[zb + tid] = sred[tid] + sred[128 + tid];
  }
}

// ---- pass B (R5 structure, verbatim — best measured: 74 us) ----
// per (b, i, s-tile of 64, d-half of 256): partial PV into Pbuf (f32); 40 KB LDS
__global__ __launch_bounds__(512, 4)
void k_passB(const f16* __restrict__ qp, const f16* __restrict__ kp,
             const f16* __restrict__ vT,
             const float* __restrict__ Z, float* __restrict__ Pbuf) {
  int bid = blockIdx.x;
  int wg = ((bid & 7) << 6) | (bid >> 3);   // XCD-aware bijective swizzle (512 = 8*64)
  int dhalf = wg & 1, st = (wg >> 1) & 7, i = (wg >> 4) & 15, b = wg >> 8;
  __shared__ __align__(16) char pool[40960];
  f16* sQ  = (f16*)pool;             // [64 s][128 c], 256B pitch, 16 KB
  f16* sKV = (f16*)(pool + 16384);   // [128][64], 128B pitch, 16 KB (K halves / vT tiles)
  f16* sE  = (f16*)(pool + 32768);   // [64 s][64 d], 128B pitch, 8 KB
  int tid = threadIdx.x, wave = tid >> 6, lane = tid & 63, lg = lane >> 4, lr = lane & 15;
  int w1m = wave >> 1, w1n = wave & 1;    // GEMM1: 4(d) x 2(s)
  int w2m = wave >> 2, w2n = wave & 3;    // GEMM2: 2(s) x 4(c)
  // this thread's K-stage duty (rows krr and krr+64, 16B slot ksl)
  int krr = tid >> 3, ksl = tid & 7;
  int lofsA = ((krr << 7) + (ksl << 4)) ^ ((krr & 7) << 4);
  int lofsB = (((krr + 64) << 7) + (ksl << 4)) ^ ((krr & 7) << 4);
  size_t qrow = (size_t)b * 8192 + i * 512 + st * 64;
  stage_rows128(qp + qrow * 128, 128, sQ, 64, tid, 512);
  floatx4 zero = {0.f, 0.f, 0.f, 0.f};
  floatx4 acc2[2][2] = {{zero, zero}, {zero, zero}};
  for (int slot = 0; slot < 5; slot++) {
    int j = i - 2 + slot;
    if (j < 0 || j > 15) continue;
    for (int dc = 0; dc < 2; dc++) {
      int dchunk = dhalf * 2 + dc;
      const f16* kb = kp + ((size_t)b * 8192 + j * 512 + dchunk * 128) * 128;
      // T14: issue cc=0 loads BEFORE the barrier
      float4 p0a = *(const float4*)(kb + krr * 128 + ksl * 8);
      float4 p0b = *(const float4*)(kb + (krr + 64) * 128 + ksl * 8);
      floatx4 acc1[2][2] = {{zero, zero}, {zero, zero}};
      __syncthreads();                       // prev readers of sKV done
      *(float4*)((char*)sKV + lofsA) = p0a;
      *(float4*)((char*)sKV + lofsB) = p0b;
      // prefetch cc=64 (lands during GEMM1(cc=0))
      float4 p1a = *(const float4*)(kb + krr * 128 + 64 + ksl * 8);
      float4 p1b = *(const float4*)(kb + (krr + 64) * 128 + 64 + ksl * 8);
      __syncthreads();
      for (int kc = 0; kc < 64; kc += 32) {  // GEMM1 over cc=0 half
        half8 ah[2];
        for (int fm = 0; fm < 2; fm++)
          ah[fm] = fragP128(sKV, w1m * 32 + fm * 16 + lr, kc + lg * 8);
        for (int fn = 0; fn < 2; fn++) {
          half8 bh = fragP256(sQ, w1n * 32 + fn * 16 + lr, kc + lg * 8);
          for (int fm = 0; fm < 2; fm++)
            acc1[fm][fn] = MFMA16(ah[fm], bh, acc1[fm][fn]);
        }
      }
      __syncthreads();
      *(float4*)((char*)sKV + lofsA) = p1a;
      *(float4*)((char*)sKV + lofsB) = p1b;
      __syncthreads();
      for (int kc = 0; kc < 64; kc += 32) {  // GEMM1 over cc=64 half
        half8 ah[2];
        for (int fm = 0; fm < 2; fm++)
          ah[fm] = fragP128(sKV, w1m * 32 + fm * 16 + lr, kc + lg * 8);
        for (int fn = 0; fn < 2; fn++) {
          half8 bh = fragP256(sQ, w1n * 32 + fn * 16 + lr, 64 + kc + lg * 8);
          for (int fm = 0; fm < 2; fm++)
            acc1[fm][fn] = MFMA16(ah[fm], bh, acc1[fm][fn]);
        }
      }
      float rz[2][4];
      {
        size_t zb = (((size_t)(b * 16 + i) * 16 + j) * 512) + dchunk * 128;
        for (int fm = 0; fm < 2; fm++) for (int jj = 0; jj < 4; jj++)
          rz[fm][jj] = 1.0f / Z[zb + w1m * 32 + fm * 16 + lg * 4 + jj];
      }
      for (int dsub = 0; dsub < 2; dsub++) {
        __syncthreads();   // prev GEMM2 done with E and KV buffers
        if ((w1m >> 1) == dsub) {
          // this half's waves write E' = exp(S)/Z (single f16)
          for (int fm = 0; fm < 2; fm++) for (int fn = 0; fn < 2; fn++)
            for (int jj = 0; jj < 4; jj++) {
              int dl = w1m * 32 + fm * 16 + lg * 4 + jj;
              int ds = dl - dsub * 64;
              int s = w1n * 32 + fn * 16 + lr;
              float e = exp2f(acc1[fm][fn][jj] * RSL2E) * rz[fm][jj];
              int ofs = ((s << 7) + (ds << 1)) ^ ((s & 7) << 4);
              *(f16*)((char*)sE + ofs) = (f16)e;
            }
        } else {
          // other 4 waves stage vT tile [128 c][64 d]
          int tt = (wave >= 4) ? (tid - 256) : tid;
          size_t vcol = (size_t)j * 512 + dchunk * 128 + dsub * 64;
          const f16* gv = vT + (size_t)b * 128 * 8192 + vcol;
          for (int idx = tt; idx < 1024; idx += 256) {
            int row = idx >> 3, sl = idx & 7;
            int lofs = ((row << 7) + (sl << 4)) ^ ((row & 7) << 4);
            *(float4*)((char*)sKV + lofs) = *(const float4*)(gv + (size_t)row * 8192 + sl * 8);
          }
        }
        __syncthreads();
        for (int kc = 0; kc < 64; kc += 32) {
          half8 ah[2];
          for (int fm = 0; fm < 2; fm++)
            ah[fm] = fragP128(sE, w2m * 32 + fm * 16 + lr, kc + lg * 8);
          for (int fn = 0; fn < 2; fn++) {
            half8 bh = fragP128(sKV, w2n * 32 + fn * 16 + lr, kc + lg * 8);
            for (int fm = 0; fm < 2; fm++)
              acc2[fm][fn] = MFMA16(ah[fm], bh, acc2[fm][fn]);
          }
        }
      }
    }
  }
  // epilogue: write f32 partial to Pbuf via LDS for coalescing
  __syncthreads();
  float* ef = (float*)pool;   // [64][128] f32 = 32 KB (overlays sQ+sKV)
  for (int fm = 0; fm < 2; fm++) for (int fn = 0; fn < 2; fn++) {
    int c = w2n * 32 + fn * 16 + lr;
    for (int jj = 0; jj < 4; jj++) {
      int s = w2m * 32 + fm * 16 + lg * 4 + jj;
      ef[s * 128 + c] = acc2[fm][fn][jj];
    }
  }
  __syncthreads();
  float* po = Pbuf + ((size_t)((((b * 16 + i) * 8 + st) * 2) + dhalf)) * 8192;
  for (int idx = tid; idx < 2048; idx += 512)
    ((float4*)po)[idx] = ((const float4*)ef)[idx];
}

extern "C" void kernel_launch(void* const* d_in, const int* in_sizes, int n_in,
                              void* d_out, int out_size, void* d_ws, size_t ws_size,
                              hipStream_t stream) {
  const float* query     = (const float*)d_in[0];
  const float* key_value = (const float*)d_in[1];
  const float* Wq  = (const float*)d_in[2];
  const float* bq  = (const float*)d_in[3];
  const float* Wkv = (const float*)d_in[4];
  const float* bkv = (const float*)d_in[5];
  const float* Wo  = (const float*)d_in[6];
  const float* bo  = (const float*)d_in[7];
  float* out = (float*)d_out;

  char* ws = (char*)d_ws;
  size_t off = 0;
  auto alloc = [&](size_t bytes) -> char* {
    char* p = ws + off;
    off += (bytes + 255) & ~(size_t)255;
    return p;
  };
  const size_t SZH = (size_t)16384 * 128 * 2;   // one f16 array over all rows
  f16* qhp  = (f16*)alloc(SZH);   // q projected, single f16
  f16* khp  = (f16*)alloc(SZH);   // k projected, single f16
  f16* vT   = (f16*)alloc(SZH);   // v projected, transposed [b][c][l], single f16
  float* Pbuf = (float*)alloc((size_t)512 * 8192 * 4);   // 16.78 MB partials
  f16* WqTh  = (f16*)alloc(32768); f16* WqTl  = (f16*)alloc(32768);
  f16* WkvTh = (f16*)alloc(65536); f16* WkvTl = (f16*)alloc(65536);
  f16* WoTh  = (f16*)alloc(32768); f16* WoTl  = (f16*)alloc(32768);
  float* Zb = (float*)alloc((size_t)2 * 16 * 16 * 512 * 4);
  float* Ub = (float*)alloc((size_t)2 * 16 * 128 * 4);
  if (off > ws_size) return;   // workspace too small: bail

  k_splitW<<<256, 256, 0, stream>>>(Wq, Wkv, Wo, WqTh, WqTl, WkvTh, WkvTl, WoTh, WoTl);
  // q projection (fused fp32 split)
  k_proj<<<256, 512, 0, stream>>>(query, WqTh, WqTl, bq, qhp, 0);
  // k projection (first 128 channels of Wkv)
  k_proj<<<256, 512, 0, stream>>>(key_value, WkvTh, WkvTl, bkv, khp, 0);
  // v projection (second 128 channels), stored transposed [b][c][l]
  k_proj<<<256, 512, 0, stream>>>(key_value, WkvTh + 128 * 128, WkvTl + 128 * 128,
                                  bkv + 128, vT, 1);
  k_U<<<256, 256, 0, stream>>>(vT, Ub);
  k_passA<<<640, 512, 0, stream>>>(khp, qhp, Zb);
  k_passB<<<512, 512, 0, stream>>>(qhp, khp, vT, Zb, Pbuf);
  k_final<<<256, 512, 0, stream>>>(Pbuf, Ub, WoTh, WoTl, bo, out);
}

// Round 10
// 126.729 us; speedup vs baseline: 1.9602x; 1.0590x over previous
//
#include <hip/hip_runtime.h>

typedef _Float16 f16;
typedef _Float16 half8 __attribute__((ext_vector_type(8)));
typedef float floatx4 __attribute__((ext_vector_type(4)));

#define MFMA16(a,b,c) __builtin_amdgcn_mfma_f32_16x16x32_f16((a),(b),(c),0,0,0)
// (1/sqrt(128)) * log2(e)
#define RSL2E 0.12751743f

__device__ __forceinline__ void split2(float x, f16 &h, f16 &l) {
  f16 hh = (f16)x;
  h = hh;
  l = (f16)(x - (float)hh);
}

// ---- LDS staging: rows of 64 halves (128B pitch), XOR-swizzled ----
__device__ __forceinline__ void stage_rows64(const f16* __restrict__ g, int gstride,
                                             f16* lds, int rows, int tid, int nthr) {
  int total = rows * 8;
  for (int idx = tid; idx < total; idx += nthr) {
    int row = idx >> 3, slot = idx & 7;
    float4 v = *(const float4*)(g + (size_t)row * gstride + slot * 8);
    int lofs = ((row << 7) + (slot << 4)) ^ ((row & 7) << 4);
    *(float4*)((char*)lds + lofs) = v;
  }
}
// rows of 128 halves (256B pitch), XOR-swizzled
__device__ __forceinline__ void stage_rows128(const f16* __restrict__ g, int gstride,
                                              f16* lds, int rows, int tid, int nthr) {
  int total = rows * 16;
  for (int idx = tid; idx < total; idx += nthr) {
    int row = idx >> 4, slot = idx & 15;
    float4 v = *(const float4*)(g + (size_t)row * gstride + slot * 8);
    int lofs = ((row << 8) + (slot << 4)) ^ ((row & 7) << 4);
    *(float4*)((char*)lds + lofs) = v;
  }
}
// stage fp32 rows with on-the-fly split into h/l tiles (64 cols, 128B pitch each)
__device__ __forceinline__ void stage_split64(const float* __restrict__ g, int gstride,
                                              f16* ldsh, f16* ldsl, int rows,
                                              int tid, int nthr) {
  int total = rows * 16;
  for (int idx = tid; idx < total; idx += nthr) {
    int row = idx >> 4, cg = idx & 15;
    float4 va = *(const float4*)(g + (size_t)row * gstride + cg * 4);
    union { f16 a[4]; uint2 u; } hh, ll;
    split2(va.x, hh.a[0], ll.a[0]);
    split2(va.y, hh.a[1], ll.a[1]);
    split2(va.z, hh.a[2], ll.a[2]);
    split2(va.w, hh.a[3], ll.a[3]);
    int lofs = ((row << 7) + (cg << 3)) ^ ((row & 7) << 4);
    *(uint2*)((char*)ldsh + lofs) = hh.u;
    *(uint2*)((char*)ldsl + lofs) = ll.u;
  }
}
__device__ __forceinline__ half8 fragP128(const f16* lds, int row, int kofs) {
  int ofs = ((row << 7) + (kofs << 1)) ^ ((row & 7) << 4);
  return *(const half8*)((const char*)lds + ofs);
}
__device__ __forceinline__ half8 fragP256(const f16* lds, int row, int kofs) {
  int ofs = ((row << 8) + (kofs << 1)) ^ ((row & 7) << 4);
  return *(const half8*)((const char*)lds + ofs);
}

// ---- transpose + split the three weight matrices ----
__global__ void k_splitW(const float* __restrict__ Wq, const float* __restrict__ Wkv,
                         const float* __restrict__ Wo,
                         f16* WqTh, f16* WqTl, f16* WkvTh, f16* WkvTl,
                         f16* WoTh, f16* WoTl) {
  int idx = blockIdx.x * 256 + threadIdx.x;
  if (idx >= 65536) return;
  float v; f16 *ph, *pl; int dst;
  if (idx < 16384) {
    int n = idx >> 7, c = idx & 127;
    v = Wq[c * 128 + n]; ph = WqTh; pl = WqTl; dst = idx;
  } else if (idx < 49152) {
    int t = idx - 16384; int n = t >> 7, c = t & 127;
    v = Wkv[c * 256 + n]; ph = WkvTh; pl = WkvTl; dst = t;
  } else {
    int t = idx - 49152; int n = t >> 7, c = t & 127;
    v = Wo[c * 128 + n]; ph = WoTh; pl = WoTl; dst = t;
  }
  f16 h, l; split2(v, h, l);
  ph[dst] = h; pl[dst] = l;
}

// ---- fused split+GEMM for all three projections in ONE dispatch (grid 768) ----
// pidx 0: q = query*Wq  (mode 0); 1: k = kv*Wkv[:,:128] (mode 0); 2: v -> vT (mode 1)
__global__ __launch_bounds__(512, 2)
void k_proj(const float* __restrict__ query, const float* __restrict__ key_value,
            const f16* __restrict__ WqTh, const f16* __restrict__ WqTl,
            const f16* __restrict__ WkvTh, const f16* __restrict__ WkvTl,
            const float* __restrict__ bq, const float* __restrict__ bkv,
            f16* __restrict__ qhp, f16* __restrict__ khp, f16* __restrict__ vT) {
  int pidx = blockIdx.x >> 8, blk = blockIdx.x & 255;
  const float* A; const f16 *BTh, *BTl; const float* bias; f16* out; int mode;
  if (pidx == 0)      { A = query;     BTh = WqTh;          BTl = WqTl;          bias = bq;        out = qhp; mode = 0; }
  else if (pidx == 1) { A = key_value; BTh = WkvTh;         BTl = WkvTl;         bias = bkv;       out = khp; mode = 0; }
  else                { A = key_value; BTh = WkvTh + 16384; BTl = WkvTl + 16384; bias = bkv + 128; out = vT;  mode = 1; }
  __shared__ f16 pool[24576];
  f16* sAh = pool;           // [64][64]
  f16* sAl = pool + 4096;
  f16* sBh = pool + 8192;    // [128][64]
  f16* sBl = pool + 16384;
  int tid = threadIdx.x, wave = tid >> 6, lane = tid & 63, lg = lane >> 4, lr = lane & 15;
  int wm = wave >> 2, wn = wave & 3;   // 2 x 4 waves, 32x32 wave tiles
  size_t rowbase = (size_t)blk * 64;
  floatx4 zero = {0.f, 0.f, 0.f, 0.f};
  floatx4 acc[2][2] = {{zero, zero}, {zero, zero}};
  for (int cc = 0; cc < 128; cc += 64) {
    __syncthreads();
    stage_split64(A + rowbase * 128 + cc, 128, sAh, sAl, 64, tid, 512);
    stage_rows64(BTh + cc, 128, sBh, 128, tid, 512);
    stage_rows64(BTl + cc, 128, sBl, 128, tid, 512);
    __syncthreads();
    for (int kc = 0; kc < 64; kc += 32) {
      half8 ah[2], al[2];
      for (int fm = 0; fm < 2; fm++) {
        ah[fm] = fragP128(sAh, wm * 32 + fm * 16 + lr, kc + lg * 8);
        al[fm] = fragP128(sAl, wm * 32 + fm * 16 + lr, kc + lg * 8);
      }
      for (int fn = 0; fn < 2; fn++) {
        half8 bh = fragP128(sBh, wn * 32 + fn * 16 + lr, kc + lg * 8);
        half8 bl = fragP128(sBl, wn * 32 + fn * 16 + lr, kc + lg * 8);
        for (int fm = 0; fm < 2; fm++) {
          acc[fm][fn] = MFMA16(ah[fm], bh, acc[fm][fn]);
          acc[fm][fn] = MFMA16(ah[fm], bl, acc[fm][fn]);
          acc[fm][fn] = MFMA16(al[fm], bh, acc[fm][fn]);
        }
      }
    }
  }
  __syncthreads();
  f16* e = pool;          // [64][136] padded, single
  for (int fm = 0; fm < 2; fm++) for (int fn = 0; fn < 2; fn++) {
    int n = wn * 32 + fn * 16 + lr;
    float bs = bias[n];
    for (int jj = 0; jj < 4; jj++) {
      int m = wm * 32 + fm * 16 + lg * 4 + jj;
      e[m * 136 + n] = (f16)(acc[fm][fn][jj] + bs);
    }
  }
  __syncthreads();
  if (mode == 0) {
    for (int idx = tid; idx < 1024; idx += 512) {
      int r = idx >> 4, sl = idx & 15;
      *(float4*)(out + (rowbase + r) * 128 + sl * 8) =
          *(const float4*)((const char*)e + r * 272 + sl * 16);
    }
  } else {
    size_t bidx = rowbase >> 13, lofs = rowbase & 8191;
    for (int idx = tid; idx < 1024; idx += 512) {
      int c = idx >> 3, sl = idx & 7;
      union { f16 a[8]; float4 v; } th;
      for (int t = 0; t < 8; t++) th.a[t] = e[(sl * 8 + t) * 136 + c];
      *(float4*)(out + (bidx * 128 + c) * 8192 + lofs + sl * 8) = th.v;
    }
  }
}

// ---- fused reduce+final projection: out fp32 = (P0+P1+P2+P3+U) * WoT^T + bo ----
__global__ __launch_bounds__(512, 2)
void k_final(const float* __restrict__ Pbuf, const float* __restrict__ U,
             const f16* __restrict__ BTh, const f16* __restrict__ BTl,
             const float* __restrict__ bias, float* __restrict__ out) {
  __shared__ f16 pool[24576];
  f16* sAh = pool;
  f16* sAl = pool + 4096;
  f16* sBh = pool + 8192;
  f16* sBl = pool + 16384;
  int tid = threadIdx.x, wave = tid >> 6, lane = tid & 63, lg = lane >> 4, lr = lane & 15;
  int wm = wave >> 2, wn = wave & 3;
  size_t rowbase = (size_t)blockIdx.x * 64;
  // map rows -> (b,i,st) -> Pbuf tile (4 d-quarter partials)
  int b = (int)(rowbase >> 13), r0 = (int)(rowbase & 8191);
  int i = r0 >> 9, st = (r0 >> 6) & 7;
  const float* p0 = Pbuf + ((size_t)(((b * 16 + i) * 8 + st) * 4)) * 8192;
  const float* p1 = p0 + 8192;
  const float* p2 = p0 + 16384;
  const float* p3 = p0 + 24576;
  const float* Ub = U + ((size_t)b * 16 + i) * 128;
  floatx4 zero = {0.f, 0.f, 0.f, 0.f};
  floatx4 acc[2][2] = {{zero, zero}, {zero, zero}};
  for (int cc = 0; cc < 128; cc += 64) {
    __syncthreads();
    // A-stage: sum partials + U, split into h/l
    for (int idx = tid; idx < 1024; idx += 512) {
      int row = idx >> 4, cg = idx & 15;
      int c = cc + cg * 4;
      float4 a0 = *(const float4*)(p0 + row * 128 + c);
      float4 a1 = *(const float4*)(p1 + row * 128 + c);
      float4 a2 = *(const float4*)(p2 + row * 128 + c);
      float4 a3 = *(const float4*)(p3 + row * 128 + c);
      float4 uu = *(const float4*)(Ub + c);
      float vals[4] = {(a0.x + a1.x) + (a2.x + a3.x) + uu.x,
                       (a0.y + a1.y) + (a2.y + a3.y) + uu.y,
                       (a0.z + a1.z) + (a2.z + a3.z) + uu.z,
                       (a0.w + a1.w) + (a2.w + a3.w) + uu.w};
      union { f16 a[4]; uint2 u; } hh, ll;
      for (int t = 0; t < 4; t++) split2(vals[t], hh.a[t], ll.a[t]);
      int lofs = ((row << 7) + (cg << 3)) ^ ((row & 7) << 4);
      *(uint2*)((char*)sAh + lofs) = hh.u;
      *(uint2*)((char*)sAl + lofs) = ll.u;
    }
    stage_rows64(BTh + cc, 128, sBh, 128, tid, 512);
    stage_rows64(BTl + cc, 128, sBl, 128, tid, 512);
    __syncthreads();
    for (int kc = 0; kc < 64; kc += 32) {
      half8 ah[2], al[2];
      for (int fm = 0; fm < 2; fm++) {
        ah[fm] = fragP128(sAh, wm * 32 + fm * 16 + lr, kc + lg * 8);
        al[fm] = fragP128(sAl, wm * 32 + fm * 16 + lr, kc + lg * 8);
      }
      for (int fn = 0; fn < 2; fn++) {
        half8 bh = fragP128(sBh, wn * 32 + fn * 16 + lr, kc + lg * 8);
        half8 bl = fragP128(sBl, wn * 32 + fn * 16 + lr, kc + lg * 8);
        for (int fm = 0; fm < 2; fm++) {
          acc[fm][fn] = MFMA16(ah[fm], bh, acc[fm][fn]);
          acc[fm][fn] = MFMA16(ah[fm], bl, acc[fm][fn]);
          acc[fm][fn] = MFMA16(al[fm], bh, acc[fm][fn]);
        }
      }
    }
  }
  __syncthreads();
  float* ef = (float*)pool;   // [64][132] padded fp32
  for (int fm = 0; fm < 2; fm++) for (int fn = 0; fn < 2; fn++) {
    int n = wn * 32 + fn * 16 + lr;
    float bs = bias[n];
    for (int jj = 0; jj < 4; jj++) {
      int m = wm * 32 + fm * 16 + lg * 4 + jj;
      ef[m * 132 + n] = acc[fm][fn][jj] + bs;
    }
  }
  __syncthreads();
  for (int idx = tid; idx < 2048; idx += 512) {
    int r = idx >> 5, sl = idx & 31;
    *(float4*)(out + (rowbase + r) * 128 + sl * 4) = *(const float4*)(ef + r * 132 + sl * 4);
  }
}

// ---- U[b][i][c] = (1/512) * sum over disallowed k-blocks of their column sums of v ----
__global__ void k_U(const f16* __restrict__ vT, float* __restrict__ U) {
  int b = blockIdx.x >> 7, c = blockIdx.x & 127;
  int tid = threadIdx.x;
  const f16* r = vT + ((size_t)b * 128 + c) * 8192;
  float s = 0.f;
  const float4* r4 = (const float4*)(r + tid * 32);
  for (int t = 0; t < 4; t++) {
    float4 v = r4[t];
    const f16* a = (const f16*)&v;
    for (int u = 0; u < 8; u++) s += (float)a[u];
  }
  __shared__ float part[256];
  __shared__ float bs[16];
  part[tid] = s;
  __syncthreads();
  if (tid < 16) {
    float t = 0.f;
    for (int u = 0; u < 16; u++) t += part[tid * 16 + u];
    bs[tid] = t;
  }
  __syncthreads();
  if (tid < 16) {
    int i = tid;
    float tot = 0.f;
    for (int j = 0; j < 16; j++) tot += bs[j];
    int j0 = i - 2 < 0 ? 0 : i - 2;
    int j1 = i + 2 > 15 ? 15 : i + 2;
    float win = 0.f;
    for (int j = j0; j <= j1; j++) win += bs[j];
    U[((size_t)b * 16 + i) * 128 + c] = (tot - win) * (1.0f / 512.0f);
  }
}

// ---- pass A: Z[b][i][j][d] = sum_s exp2(RSL2E * (k_d . q_s)), single f16 inputs ----
__global__ __launch_bounds__(512, 4)
void k_passA(const f16* __restrict__ kp, const f16* __restrict__ qp,
             float* __restrict__ Z) {
  int bid = blockIdx.x;
  int wg = (bid & 7) * 80 + (bid >> 3);     // XCD-aware bijective swizzle (640 = 8*80)
  int dchunk = wg & 3; int rest = wg >> 2;
  int slot = rest % 5; int rest2 = rest / 5;
  int i = rest2 & 15; int b = rest2 >> 4;
  int j = i - 2 + slot;
  if (j < 0 || j > 15) return;
  __shared__ f16 sK[16384], sQ[16384];  // 64 KiB -> 2 WG/CU
  int tid = threadIdx.x, wave = tid >> 6, lane = tid & 63, lg = lane >> 4, lr = lane & 15;
  int wm = wave >> 1, wn = wave & 1;   // 4 x 2 waves; wave tile 32(d) x 64(s)
  size_t krow = (size_t)b * 8192 + j * 512 + dchunk * 128;
  stage_rows128(kp + krow * 128, 128, sK, 128, tid, 512);
  float zp[2][4] = {{0.f,0.f,0.f,0.f},{0.f,0.f,0.f,0.f}};
  floatx4 zero = {0.f, 0.f, 0.f, 0.f};
  for (int sc = 0; sc < 4; sc++) {
    __syncthreads();
    size_t qrow = (size_t)b * 8192 + i * 512 + sc * 128;
    stage_rows128(qp + qrow * 128, 128, sQ, 128, tid, 512);
    __syncthreads();
    floatx4 acc[2][4] = {{zero,zero,zero,zero},{zero,zero,zero,zero}};
    for (int kc = 0; kc < 128; kc += 32) {
      half8 ah[2];
      for (int fm = 0; fm < 2; fm++)
        ah[fm] = fragP256(sK, wm * 32 + fm * 16 + lr, kc + lg * 8);
      for (int fn = 0; fn < 4; fn++) {
        half8 bh = fragP256(sQ, wn * 64 + fn * 16 + lr, kc + lg * 8);
        for (int fm = 0; fm < 2; fm++)
          acc[fm][fn] = MFMA16(ah[fm], bh, acc[fm][fn]);
      }
    }
    for (int fm = 0; fm < 2; fm++) for (int fn = 0; fn < 4; fn++)
      for (int jj = 0; jj < 4; jj++)
        zp[fm][jj] += exp2f(acc[fm][fn][jj] * RSL2E);
  }
  // in-wave butterfly over lr (16 s-columns)
  for (int off = 1; off < 16; off <<= 1)
    for (int fm = 0; fm < 2; fm++) for (int jj = 0; jj < 4; jj++)
      zp[fm][jj] += __shfl_xor(zp[fm][jj], off, 64);
  // cross-wave combine of the two wn halves via LDS
  __syncthreads();
  float* sred = (float*)sQ;      // 256 floats
  if (lr == 0) {
    for (int fm = 0; fm < 2; fm++) for (int jj = 0; jj < 4; jj++) {
      int d = wm * 32 + fm * 16 + lg * 4 + jj;
      sred[wn * 128 + d] = zp[fm][jj];
    }
  }
  __syncthreads();
  if (tid < 128) {
    size_t zb = (((size_t)(b * 16 + i) * 16 + j) * 512) + dchunk * 128;
    Z[zb + tid] = sred[tid] + sred[128 + tid];
  }
}

// ---- pass B (R5 structure; d split into QUARTERS -> grid 1024 = 4 blocks/CU) ----
// per (b, i, s-tile of 64, d-quarter of 128): partial PV into Pbuf (f32); 40 KB LDS
__global__ __launch_bounds__(512, 4)
void k_passB(const f16* __restrict__ qp, const f16* __restrict__ kp,
             const f16* __restrict__ vT,
             const float* __restrict__ Z, float* __restrict__ Pbuf) {
  int bid = blockIdx.x;
  int wg = ((bid & 7) << 7) | (bid >> 3);   // XCD-aware bijective swizzle (1024 = 8*128)
  int dq = wg & 3, st = (wg >> 2) & 7, i = (wg >> 5) & 15, b = wg >> 9;
  __shared__ __align__(16) char pool[40960];
  f16* sQ  = (f16*)pool;             // [64 s][128 c], 256B pitch, 16 KB
  f16* sKV = (f16*)(pool + 16384);   // [128][64], 128B pitch, 16 KB (K halves / vT tiles)
  f16* sE  = (f16*)(pool + 32768);   // [64 s][64 d], 128B pitch, 8 KB
  int tid = threadIdx.x, wave = tid >> 6, lane = tid & 63, lg = lane >> 4, lr = lane & 15;
  int w1m = wave >> 1, w1n = wave & 1;    // GEMM1: 4(d) x 2(s)
  int w2m = wave >> 2, w2n = wave & 3;    // GEMM2: 2(s) x 4(c)
  // this thread's K-stage duty (rows krr and krr+64, 16B slot ksl)
  int krr = tid >> 3, ksl = tid & 7;
  int lofsA = ((krr << 7) + (ksl << 4)) ^ ((krr & 7) << 4);
  int lofsB = (((krr + 64) << 7) + (ksl << 4)) ^ ((krr & 7) << 4);
  size_t qrow = (size_t)b * 8192 + i * 512 + st * 64;
  stage_rows128(qp + qrow * 128, 128, sQ, 64, tid, 512);
  floatx4 zero = {0.f, 0.f, 0.f, 0.f};
  floatx4 acc2[2][2] = {{zero, zero}, {zero, zero}};
  for (int slot = 0; slot < 5; slot++) {
    int j = i - 2 + slot;
    if (j < 0 || j > 15) continue;
    {
      int dchunk = dq;
      const f16* kb = kp + ((size_t)b * 8192 + j * 512 + dchunk * 128) * 128;
      // T14: issue cc=0 loads BEFORE the barrier
      float4 p0a = *(const float4*)(kb + krr * 128 + ksl * 8);
      float4 p0b = *(const float4*)(kb + (krr + 64) * 128 + ksl * 8);
      floatx4 acc1[2][2] = {{zero, zero}, {zero, zero}};
      __syncthreads();                       // prev readers of sKV done
      *(float4*)((char*)sKV + lofsA) = p0a;
      *(float4*)((char*)sKV + lofsB) = p0b;
      // prefetch cc=64 (lands during GEMM1(cc=0))
      float4 p1a = *(const float4*)(kb + krr * 128 + 64 + ksl * 8);
      float4 p1b = *(const float4*)(kb + (krr + 64) * 128 + 64 + ksl * 8);
      __syncthreads();
      for (int kc = 0; kc < 64; kc += 32) {  // GEMM1 over cc=0 half
        half8 ah[2];
        for (int fm = 0; fm < 2; fm++)
          ah[fm] = fragP128(sKV, w1m * 32 + fm * 16 + lr, kc + lg * 8);
        for (int fn = 0; fn < 2; fn++) {
          half8 bh = fragP256(sQ, w1n * 32 + fn * 16 + lr, kc + lg * 8);
          for (int fm = 0; fm < 2; fm++)
            acc1[fm][fn] = MFMA16(ah[fm], bh, acc1[fm][fn]);
        }
      }
      __syncthreads();
      *(float4*)((char*)sKV + lofsA) = p1a;
      *(float4*)((char*)sKV + lofsB) = p1b;
      __syncthreads();
      for (int kc = 0; kc < 64; kc += 32) {  // GEMM1 over cc=64 half
        half8 ah[2];
        for (int fm = 0; fm < 2; fm++)
          ah[fm] = fragP128(sKV, w1m * 32 + fm * 16 + lr, kc + lg * 8);
        for (int fn = 0; fn < 2; fn++) {
          half8 bh = fragP256(sQ, w1n * 32 + fn * 16 + lr, 64 + kc + lg * 8);
          for (int fm = 0; fm < 2; fm++)
            acc1[fm][fn] = MFMA16(ah[fm], bh, acc1[fm][fn]);
        }
      }
      float rz[2][4];
      {
        size_t zb = (((size_t)(b * 16 + i) * 16 + j) * 512) + dchunk * 128;
        for (int fm = 0; fm < 2; fm++) for (int jj = 0; jj < 4; jj++)
          rz[fm][jj] = 1.0f / Z[zb + w1m * 32 + fm * 16 + lg * 4 + jj];
      }
      for (int dsub = 0; dsub < 2; dsub++) {
        __syncthreads();   // prev GEMM2 done with E and KV buffers
        if ((w1m >> 1) == dsub) {
          // this half's waves write E' = exp(S)/Z (single f16)
          for (int fm = 0; fm < 2; fm++) for (int fn = 0; fn < 2; fn++)
            for (int jj = 0; jj < 4; jj++) {
              int dl = w1m * 32 + fm * 16 + lg * 4 + jj;
              int ds = dl - dsub * 64;
              int s = w1n * 32 + fn * 16 + lr;
              float e = exp2f(acc1[fm][fn][jj] * RSL2E) * rz[fm][jj];
              int ofs = ((s << 7) + (ds << 1)) ^ ((s & 7) << 4);
              *(f16*)((char*)sE + ofs) = (f16)e;
            }
        } else {
          // other 4 waves stage vT tile [128 c][64 d]
          int tt = (wave >= 4) ? (tid - 256) : tid;
          size_t vcol = (size_t)j * 512 + dchunk * 128 + dsub * 64;
          const f16* gv = vT + (size_t)b * 128 * 8192 + vcol;
          for (int idx = tt; idx < 1024; idx += 256) {
            int row = idx >> 3, sl = idx & 7;
            int lofs = ((row << 7) + (sl << 4)) ^ ((row & 7) << 4);
            *(float4*)((char*)sKV + lofs) = *(const float4*)(gv + (size_t)row * 8192 + sl * 8);
          }
        }
        __syncthreads();
        for (int kc = 0; kc < 64; kc += 32) {
          half8 ah[2];
          for (int fm = 0; fm < 2; fm++)
            ah[fm] = fragP128(sE, w2m * 32 + fm * 16 + lr, kc + lg * 8);
          for (int fn = 0; fn < 2; fn++) {
            half8 bh = fragP128(sKV, w2n * 32 + fn * 16 + lr, kc + lg * 8);
            for (int fm = 0; fm < 2; fm++)
              acc2[fm][fn] = MFMA16(ah[fm], bh, acc2[fm][fn]);
          }
        }
      }
    }
  }
  // epilogue: write f32 partial to Pbuf via LDS for coalescing
  __syncthreads();
  float* ef = (float*)pool;   // [64][128] f32 = 32 KB (overlays sQ+sKV)
  for (int fm = 0; fm < 2; fm++) for (int fn = 0; fn < 2; fn++) {
    int c = w2n * 32 + fn * 16 + lr;
    for (int jj = 0; jj < 4; jj++) {
      int s = w2m * 32 + fm * 16 + lg * 4 + jj;
      ef[s * 128 + c] = acc2[fm][fn][jj];
    }
  }
  __syncthreads();
  float* po = Pbuf + ((size_t)((((b * 16 + i) * 8 + st) * 4) + dq)) * 8192;
  for (int idx = tid; idx < 2048; idx += 512)
    ((float4*)po)[idx] = ((const float4*)ef)[idx];
}

extern "C" void kernel_launch(void* const* d_in, const int* in_sizes, int n_in,
                              void* d_out, int out_size, void* d_ws, size_t ws_size,
                              hipStream_t stream) {
  const float* query     = (const float*)d_in[0];
  const float* key_value = (const float*)d_in[1];
  const float* Wq  = (const float*)d_in[2];
  const float* bq  = (const float*)d_in[3];
  const float* Wkv = (const float*)d_in[4];
  const float* bkv = (const float*)d_in[5];
  const float* Wo  = (const float*)d_in[6];
  const float* bo  = (const float*)d_in[7];
  float* out = (float*)d_out;

  char* ws = (char*)d_ws;
  size_t off = 0;
  auto alloc = [&](size_t bytes) -> char* {
    char* p = ws + off;
    off += (bytes + 255) & ~(size_t)255;
    return p;
  };
  const size_t SZH = (size_t)16384 * 128 * 2;   // one f16 array over all rows
  f16* qhp  = (f16*)alloc(SZH);   // q projected, single f16
  f16* khp  = (f16*)alloc(SZH);   // k projected, single f16
  f16* vT   = (f16*)alloc(SZH);   // v projected, transposed [b][c][l], single f16
  float* Pbuf = (float*)alloc((size_t)1024 * 8192 * 4);   // 33.5 MB partials (4 d-quarters)
  f16* WqTh  = (f16*)alloc(32768); f16* WqTl  = (f16*)alloc(32768);
  f16* WkvTh = (f16*)alloc(65536); f16* WkvTl = (f16*)alloc(65536);
  f16* WoTh  = (f16*)alloc(32768); f16* WoTl  = (f16*)alloc(32768);
  float* Zb = (float*)alloc((size_t)2 * 16 * 16 * 512 * 4);
  float* Ub = (float*)alloc((size_t)2 * 16 * 128 * 4);
  if (off > ws_size) return;   // workspace too small: bail

  k_splitW<<<256, 256, 0, stream>>>(Wq, Wkv, Wo, WqTh, WqTl, WkvTh, WkvTl, WoTh, WoTl);
  // all three projections in one dispatch (q / k / v->vT)
  k_proj<<<768, 512, 0, stream>>>(query, key_value, WqTh, WqTl, WkvTh, WkvTl,
                                  bq, bkv, qhp, khp, vT);
  k_U<<<256, 256, 0, stream>>>(vT, Ub);
  k_passA<<<640, 512, 0, stream>>>(khp, qhp, Zb);
  k_passB<<<1024, 512, 0, stream>>>(qhp, khp, vT, Zb, Pbuf);
  k_final<<<256, 512, 0, stream>>>(Pbuf, Ub, WoTh, WoTl, bo, out);
}

// Round 11
// 113.396 us; speedup vs baseline: 2.1907x; 1.1176x over previous
//
#include <hip/hip_runtime.h>

typedef _Float16 f16;
typedef _Float16 half8 __attribute__((ext_vector_type(8)));
typedef float floatx4 __attribute__((ext_vector_type(4)));

#define MFMA16(a,b,c) __builtin_amdgcn_mfma_f32_16x16x32_f16((a),(b),(c),0,0,0)
// (1/sqrt(128)) * log2(e)
#define RSL2E 0.12751743f

__device__ __forceinline__ void split2(float x, f16 &h, f16 &l) {
  f16 hh = (f16)x;
  h = hh;
  l = (f16)(x - (float)hh);
}

// ---- LDS staging: rows of 64 halves (128B pitch), XOR-swizzled ----
__device__ __forceinline__ void stage_rows64(const f16* __restrict__ g, int gstride,
                                             f16* lds, int rows, int tid, int nthr) {
  int total = rows * 8;
  for (int idx = tid; idx < total; idx += nthr) {
    int row = idx >> 3, slot = idx & 7;
    float4 v = *(const float4*)(g + (size_t)row * gstride + slot * 8);
    int lofs = ((row << 7) + (slot << 4)) ^ ((row & 7) << 4);
    *(float4*)((char*)lds + lofs) = v;
  }
}
// rows of 128 halves (256B pitch), XOR-swizzled
__device__ __forceinline__ void stage_rows128(const f16* __restrict__ g, int gstride,
                                              f16* lds, int rows, int tid, int nthr) {
  int total = rows * 16;
  for (int idx = tid; idx < total; idx += nthr) {
    int row = idx >> 4, slot = idx & 15;
    float4 v = *(const float4*)(g + (size_t)row * gstride + slot * 8);
    int lofs = ((row << 8) + (slot << 4)) ^ ((row & 7) << 4);
    *(float4*)((char*)lds + lofs) = v;
  }
}
// stage fp32 rows with on-the-fly split into h/l tiles (64 cols, 128B pitch each)
__device__ __forceinline__ void stage_split64(const float* __restrict__ g, int gstride,
                                              f16* ldsh, f16* ldsl, int rows,
                                              int tid, int nthr) {
  int total = rows * 16;
  for (int idx = tid; idx < total; idx += nthr) {
    int row = idx >> 4, cg = idx & 15;
    float4 va = *(const float4*)(g + (size_t)row * gstride + cg * 4);
    union { f16 a[4]; uint2 u; } hh, ll;
    split2(va.x, hh.a[0], ll.a[0]);
    split2(va.y, hh.a[1], ll.a[1]);
    split2(va.z, hh.a[2], ll.a[2]);
    split2(va.w, hh.a[3], ll.a[3]);
    int lofs = ((row << 7) + (cg << 3)) ^ ((row & 7) << 4);
    *(uint2*)((char*)ldsh + lofs) = hh.u;
    *(uint2*)((char*)ldsl + lofs) = ll.u;
  }
}
__device__ __forceinline__ half8 fragP128(const f16* lds, int row, int kofs) {
  int ofs = ((row << 7) + (kofs << 1)) ^ ((row & 7) << 4);
  return *(const half8*)((const char*)lds + ofs);
}
__device__ __forceinline__ half8 fragP256(const f16* lds, int row, int kofs) {
  int ofs = ((row << 8) + (kofs << 1)) ^ ((row & 7) << 4);
  return *(const half8*)((const char*)lds + ofs);
}

// ---- transpose + split the three weight matrices ----
__global__ void k_splitW(const float* __restrict__ Wq, const float* __restrict__ Wkv,
                         const float* __restrict__ Wo,
                         f16* WqTh, f16* WqTl, f16* WkvTh, f16* WkvTl,
                         f16* WoTh, f16* WoTl) {
  int idx = blockIdx.x * 256 + threadIdx.x;
  if (idx >= 65536) return;
  float v; f16 *ph, *pl; int dst;
  if (idx < 16384) {
    int n = idx >> 7, c = idx & 127;
    v = Wq[c * 128 + n]; ph = WqTh; pl = WqTl; dst = idx;
  } else if (idx < 49152) {
    int t = idx - 16384; int n = t >> 7, c = t & 127;
    v = Wkv[c * 256 + n]; ph = WkvTh; pl = WkvTl; dst = t;
  } else {
    int t = idx - 49152; int n = t >> 7, c = t & 127;
    v = Wo[c * 128 + n]; ph = WoTh; pl = WoTl; dst = t;
  }
  f16 h, l; split2(v, h, l);
  ph[dst] = h; pl[dst] = l;
}

// ---- fused split+GEMM for all three projections in ONE dispatch (grid 768) ----
// pidx 0: q = query*Wq  (mode 0); 1: k = kv*Wkv[:,:128] (mode 0); 2: v -> vT (mode 1)
__global__ __launch_bounds__(512, 2)
void k_proj(const float* __restrict__ query, const float* __restrict__ key_value,
            const f16* __restrict__ WqTh, const f16* __restrict__ WqTl,
            const f16* __restrict__ WkvTh, const f16* __restrict__ WkvTl,
            const float* __restrict__ bq, const float* __restrict__ bkv,
            f16* __restrict__ qhp, f16* __restrict__ khp, f16* __restrict__ vT) {
  int pidx = blockIdx.x >> 8, blk = blockIdx.x & 255;
  const float* A; const f16 *BTh, *BTl; const float* bias; f16* out; int mode;
  if (pidx == 0)      { A = query;     BTh = WqTh;          BTl = WqTl;          bias = bq;        out = qhp; mode = 0; }
  else if (pidx == 1) { A = key_value; BTh = WkvTh;         BTl = WkvTl;         bias = bkv;       out = khp; mode = 0; }
  else                { A = key_value; BTh = WkvTh + 16384; BTl = WkvTl + 16384; bias = bkv + 128; out = vT;  mode = 1; }
  __shared__ f16 pool[24576];
  f16* sAh = pool;           // [64][64]
  f16* sAl = pool + 4096;
  f16* sBh = pool + 8192;    // [128][64]
  f16* sBl = pool + 16384;
  int tid = threadIdx.x, wave = tid >> 6, lane = tid & 63, lg = lane >> 4, lr = lane & 15;
  int wm = wave >> 2, wn = wave & 3;   // 2 x 4 waves, 32x32 wave tiles
  size_t rowbase = (size_t)blk * 64;
  floatx4 zero = {0.f, 0.f, 0.f, 0.f};
  floatx4 acc[2][2] = {{zero, zero}, {zero, zero}};
  for (int cc = 0; cc < 128; cc += 64) {
    __syncthreads();
    stage_split64(A + rowbase * 128 + cc, 128, sAh, sAl, 64, tid, 512);
    stage_rows64(BTh + cc, 128, sBh, 128, tid, 512);
    stage_rows64(BTl + cc, 128, sBl, 128, tid, 512);
    __syncthreads();
    for (int kc = 0; kc < 64; kc += 32) {
      half8 ah[2], al[2];
      for (int fm = 0; fm < 2; fm++) {
        ah[fm] = fragP128(sAh, wm * 32 + fm * 16 + lr, kc + lg * 8);
        al[fm] = fragP128(sAl, wm * 32 + fm * 16 + lr, kc + lg * 8);
      }
      for (int fn = 0; fn < 2; fn++) {
        half8 bh = fragP128(sBh, wn * 32 + fn * 16 + lr, kc + lg * 8);
        half8 bl = fragP128(sBl, wn * 32 + fn * 16 + lr, kc + lg * 8);
        for (int fm = 0; fm < 2; fm++) {
          acc[fm][fn] = MFMA16(ah[fm], bh, acc[fm][fn]);
          acc[fm][fn] = MFMA16(ah[fm], bl, acc[fm][fn]);
          acc[fm][fn] = MFMA16(al[fm], bh, acc[fm][fn]);
        }
      }
    }
  }
  __syncthreads();
  f16* e = pool;          // [64][136] padded, single
  for (int fm = 0; fm < 2; fm++) for (int fn = 0; fn < 2; fn++) {
    int n = wn * 32 + fn * 16 + lr;
    float bs = bias[n];
    for (int jj = 0; jj < 4; jj++) {
      int m = wm * 32 + fm * 16 + lg * 4 + jj;
      e[m * 136 + n] = (f16)(acc[fm][fn][jj] + bs);
    }
  }
  __syncthreads();
  if (mode == 0) {
    for (int idx = tid; idx < 1024; idx += 512) {
      int r = idx >> 4, sl = idx & 15;
      *(float4*)(out + (rowbase + r) * 128 + sl * 8) =
          *(const float4*)((const char*)e + r * 272 + sl * 16);
    }
  } else {
    size_t bidx = rowbase >> 13, lofs = rowbase & 8191;
    for (int idx = tid; idx < 1024; idx += 512) {
      int c = idx >> 3, sl = idx & 7;
      union { f16 a[8]; float4 v; } th;
      for (int t = 0; t < 8; t++) th.a[t] = e[(sl * 8 + t) * 136 + c];
      *(float4*)(out + (bidx * 128 + c) * 8192 + lofs + sl * 8) = th.v;
    }
  }
}

// ---- fused reduce+final projection: out fp32 = (P0+P1+P2+P3+U) * WoT^T + bo ----
__global__ __launch_bounds__(512, 2)
void k_final(const float* __restrict__ Pbuf, const float* __restrict__ U,
             const f16* __restrict__ BTh, const f16* __restrict__ BTl,
             const float* __restrict__ bias, float* __restrict__ out) {
  __shared__ f16 pool[24576];
  f16* sAh = pool;
  f16* sAl = pool + 4096;
  f16* sBh = pool + 8192;
  f16* sBl = pool + 16384;
  int tid = threadIdx.x, wave = tid >> 6, lane = tid & 63, lg = lane >> 4, lr = lane & 15;
  int wm = wave >> 2, wn = wave & 3;
  size_t rowbase = (size_t)blockIdx.x * 64;
  // map rows -> (b,i,st) -> Pbuf tile (4 d-quarter partials)
  int b = (int)(rowbase >> 13), r0 = (int)(rowbase & 8191);
  int i = r0 >> 9, st = (r0 >> 6) & 7;
  const float* p0 = Pbuf + ((size_t)(((b * 16 + i) * 8 + st) * 4)) * 8192;
  const float* p1 = p0 + 8192;
  const float* p2 = p0 + 16384;
  const float* p3 = p0 + 24576;
  const float* Ub = U + ((size_t)b * 16 + i) * 128;
  floatx4 zero = {0.f, 0.f, 0.f, 0.f};
  floatx4 acc[2][2] = {{zero, zero}, {zero, zero}};
  for (int cc = 0; cc < 128; cc += 64) {
    __syncthreads();
    // A-stage: sum partials + U, split into h/l
    for (int idx = tid; idx < 1024; idx += 512) {
      int row = idx >> 4, cg = idx & 15;
      int c = cc + cg * 4;
      float4 a0 = *(const float4*)(p0 + row * 128 + c);
      float4 a1 = *(const float4*)(p1 + row * 128 + c);
      float4 a2 = *(const float4*)(p2 + row * 128 + c);
      float4 a3 = *(const float4*)(p3 + row * 128 + c);
      float4 uu = *(const float4*)(Ub + c);
      float vals[4] = {(a0.x + a1.x) + (a2.x + a3.x) + uu.x,
                       (a0.y + a1.y) + (a2.y + a3.y) + uu.y,
                       (a0.z + a1.z) + (a2.z + a3.z) + uu.z,
                       (a0.w + a1.w) + (a2.w + a3.w) + uu.w};
      union { f16 a[4]; uint2 u; } hh, ll;
      for (int t = 0; t < 4; t++) split2(vals[t], hh.a[t], ll.a[t]);
      int lofs = ((row << 7) + (cg << 3)) ^ ((row & 7) << 4);
      *(uint2*)((char*)sAh + lofs) = hh.u;
      *(uint2*)((char*)sAl + lofs) = ll.u;
    }
    stage_rows64(BTh + cc, 128, sBh, 128, tid, 512);
    stage_rows64(BTl + cc, 128, sBl, 128, tid, 512);
    __syncthreads();
    for (int kc = 0; kc < 64; kc += 32) {
      half8 ah[2], al[2];
      for (int fm = 0; fm < 2; fm++) {
        ah[fm] = fragP128(sAh, wm * 32 + fm * 16 + lr, kc + lg * 8);
        al[fm] = fragP128(sAl, wm * 32 + fm * 16 + lr, kc + lg * 8);
      }
      for (int fn = 0; fn < 2; fn++) {
        half8 bh = fragP128(sBh, wn * 32 + fn * 16 + lr, kc + lg * 8);
        half8 bl = fragP128(sBl, wn * 32 + fn * 16 + lr, kc + lg * 8);
        for (int fm = 0; fm < 2; fm++) {
          acc[fm][fn] = MFMA16(ah[fm], bh, acc[fm][fn]);
          acc[fm][fn] = MFMA16(ah[fm], bl, acc[fm][fn]);
          acc[fm][fn] = MFMA16(al[fm], bh, acc[fm][fn]);
        }
      }
    }
  }
  __syncthreads();
  float* ef = (float*)pool;   // [64][132] padded fp32
  for (int fm = 0; fm < 2; fm++) for (int fn = 0; fn < 2; fn++) {
    int n = wn * 32 + fn * 16 + lr;
    float bs = bias[n];
    for (int jj = 0; jj < 4; jj++) {
      int m = wm * 32 + fm * 16 + lg * 4 + jj;
      ef[m * 132 + n] = acc[fm][fn][jj] + bs;
    }
  }
  __syncthreads();
  for (int idx = tid; idx < 2048; idx += 512) {
    int r = idx >> 5, sl = idx & 31;
    *(float4*)(out + (rowbase + r) * 128 + sl * 4) = *(const float4*)(ef + r * 132 + sl * 4);
  }
}

// ---- U[b][i][c] = (1/512) * sum over disallowed k-blocks of their column sums of v ----
__global__ void k_U(const f16* __restrict__ vT, float* __restrict__ U) {
  int b = blockIdx.x >> 7, c = blockIdx.x & 127;
  int tid = threadIdx.x;
  const f16* r = vT + ((size_t)b * 128 + c) * 8192;
  float s = 0.f;
  const float4* r4 = (const float4*)(r + tid * 32);
  for (int t = 0; t < 4; t++) {
    float4 v = r4[t];
    const f16* a = (const f16*)&v;
    for (int u = 0; u < 8; u++) s += (float)a[u];
  }
  __shared__ float part[256];
  __shared__ float bs[16];
  part[tid] = s;
  __syncthreads();
  if (tid < 16) {
    float t = 0.f;
    for (int u = 0; u < 16; u++) t += part[tid * 16 + u];
    bs[tid] = t;
  }
  __syncthreads();
  if (tid < 16) {
    int i = tid;
    float tot = 0.f;
    for (int j = 0; j < 16; j++) tot += bs[j];
    int j0 = i - 2 < 0 ? 0 : i - 2;
    int j1 = i + 2 > 15 ? 15 : i + 2;
    float win = 0.f;
    for (int j = j0; j <= j1; j++) win += bs[j];
    U[((size_t)b * 16 + i) * 128 + c] = (tot - win) * (1.0f / 512.0f);
  }
}

// ---- pass A: Z[b][i][j][d] = sum_s exp2(RSL2E * (k_d . q_s)), single f16 inputs ----
__global__ __launch_bounds__(512, 4)
void k_passA(const f16* __restrict__ kp, const f16* __restrict__ qp,
             float* __restrict__ Z) {
  int bid = blockIdx.x;
  int wg = (bid & 7) * 80 + (bid >> 3);     // XCD-aware bijective swizzle (640 = 8*80)
  int dchunk = wg & 3; int rest = wg >> 2;
  int slot = rest % 5; int rest2 = rest / 5;
  int i = rest2 & 15; int b = rest2 >> 4;
  int j = i - 2 + slot;
  if (j < 0 || j > 15) return;
  __shared__ f16 sK[16384], sQ[16384];  // 64 KiB -> 2 WG/CU
  int tid = threadIdx.x, wave = tid >> 6, lane = tid & 63, lg = lane >> 4, lr = lane & 15;
  int wm = wave >> 1, wn = wave & 1;   // 4 x 2 waves; wave tile 32(d) x 64(s)
  size_t krow = (size_t)b * 8192 + j * 512 + dchunk * 128;
  stage_rows128(kp + krow * 128, 128, sK, 128, tid, 512);
  float zp[2][4] = {{0.f,0.f,0.f,0.f},{0.f,0.f,0.f,0.f}};
  floatx4 zero = {0.f, 0.f, 0.f, 0.f};
  for (int sc = 0; sc < 4; sc++) {
    __syncthreads();
    size_t qrow = (size_t)b * 8192 + i * 512 + sc * 128;
    stage_rows128(qp + qrow * 128, 128, sQ, 128, tid, 512);
    __syncthreads();
    floatx4 acc[2][4] = {{zero,zero,zero,zero},{zero,zero,zero,zero}};
    for (int kc = 0; kc < 128; kc += 32) {
      half8 ah[2];
      for (int fm = 0; fm < 2; fm++)
        ah[fm] = fragP256(sK, wm * 32 + fm * 16 + lr, kc + lg * 8);
      for (int fn = 0; fn < 4; fn++) {
        half8 bh = fragP256(sQ, wn * 64 + fn * 16 + lr, kc + lg * 8);
        for (int fm = 0; fm < 2; fm++)
          acc[fm][fn] = MFMA16(ah[fm], bh, acc[fm][fn]);
      }
    }
    for (int fm = 0; fm < 2; fm++) for (int fn = 0; fn < 4; fn++)
      for (int jj = 0; jj < 4; jj++)
        zp[fm][jj] += exp2f(acc[fm][fn][jj] * RSL2E);
  }
  // in-wave butterfly over lr (16 s-columns)
  for (int off = 1; off < 16; off <<= 1)
    for (int fm = 0; fm < 2; fm++) for (int jj = 0; jj < 4; jj++)
      zp[fm][jj] += __shfl_xor(zp[fm][jj], off, 64);
  // cross-wave combine of the two wn halves via LDS
  __syncthreads();
  float* sred = (float*)sQ;      // 256 floats
  if (lr == 0) {
    for (int fm = 0; fm < 2; fm++) for (int jj = 0; jj < 4; jj++) {
      int d = wm * 32 + fm * 16 + lg * 4 + jj;
      sred[wn * 128 + d] = zp[fm][jj];
    }
  }
  __syncthreads();
  if (tid < 128) {
    size_t zb = (((size_t)(b * 16 + i) * 16 + j) * 512) + dchunk * 128;
    Z[zb + tid] = sred[tid] + sred[128 + tid];
  }
}

// ---- pass B: R5 inner structure + uniform V/Z prefetch + packed E-writes ----
// per (b, i, s-tile of 64, d-quarter of 128): partial PV into Pbuf (f32); 40 KB LDS
__global__ __launch_bounds__(512, 4)
void k_passB(const f16* __restrict__ qp, const f16* __restrict__ kp,
             const f16* __restrict__ vT,
             const float* __restrict__ Z, float* __restrict__ Pbuf) {
  int bid = blockIdx.x;
  int wg = ((bid & 7) << 7) | (bid >> 3);   // XCD-aware bijective swizzle (1024 = 8*128)
  int dq = wg & 3, st = (wg >> 2) & 7, i = (wg >> 5) & 15, b = wg >> 9;
  __shared__ __align__(16) char pool[40960];
  f16* sQ  = (f16*)pool;             // [64 s][128 c], 256B pitch, 16 KB
  f16* sKV = (f16*)(pool + 16384);   // [128][64], 128B pitch, 16 KB (K halves / vT tiles)
  f16* sE  = (f16*)(pool + 32768);   // [64 s][64 d], 128B pitch, 8 KB
  int tid = threadIdx.x, wave = tid >> 6, lane = tid & 63, lg = lane >> 4, lr = lane & 15;
  int w1m = wave >> 1, w1n = wave & 1;    // GEMM1: 4(d) x 2(s)
  int w2m = wave >> 2, w2n = wave & 3;    // GEMM2: 2(s) x 4(c)
  // K-stage duty (rows krr and krr+64, 16B slot ksl)
  int krr = tid >> 3, ksl = tid & 7;
  int lofsA = ((krr << 7) + (ksl << 4)) ^ ((krr & 7) << 4);
  int lofsB = (((krr + 64) << 7) + (ksl << 4)) ^ ((krr & 7) << 4);
  // V-stage duty: each wave stages exactly ONE dsub per iteration
  // (writer for dsub == wave>>2, so waves 0-3 stage dsub=1, waves 4-7 stage dsub=0)
  int myVdsub = (wave < 4) ? 1 : 0;
  int tt = (wave >= 4) ? (tid - 256) : tid;   // stager index within its 4-wave group
  int vr0 = tt >> 3, vsl = tt & 7;
  int vlofs[4];
  #pragma unroll
  for (int t = 0; t < 4; t++)
    vlofs[t] = (((vr0 + 32 * t) << 7) + (vsl << 4)) ^ ((vr0 & 7) << 4);
  size_t qrow = (size_t)b * 8192 + i * 512 + st * 64;
  stage_rows128(qp + qrow * 128, 128, sQ, 64, tid, 512);
  floatx4 zero = {0.f, 0.f, 0.f, 0.f};
  floatx4 acc2[2][2] = {{zero, zero}, {zero, zero}};
  const f16* vbase = vT + (size_t)b * 1048576;
  for (int slot = 0; slot < 5; slot++) {
    int j = i - 2 + slot;
    if (j < 0 || j > 15) continue;
    {
      int dchunk = dq;
      const f16* kb = kp + ((size_t)b * 8192 + j * 512 + dchunk * 128) * 128;
      // ---- iteration-start prefetches (hide global latency under barriers/MFMA) ----
      // K cc=0 half
      float4 p0a = *(const float4*)(kb + krr * 128 + ksl * 8);
      float4 p0b = *(const float4*)(kb + (krr + 64) * 128 + ksl * 8);
      // V tile for this wave's staging dsub (uniform 16 VGPR)
      const f16* gv = vbase + (size_t)j * 512 + dchunk * 128 + myVdsub * 64;
      float4 vr_0 = *(const float4*)(gv + (size_t)vr0 * 8192 + vsl * 8);
      float4 vr_1 = *(const float4*)(gv + (size_t)(vr0 + 32) * 8192 + vsl * 8);
      float4 vr_2 = *(const float4*)(gv + (size_t)(vr0 + 64) * 8192 + vsl * 8);
      float4 vr_3 = *(const float4*)(gv + (size_t)(vr0 + 96) * 8192 + vsl * 8);
      // Z reciprocals (this wave's 8 values)
      float rz[2][4];
      {
        size_t zb = (((size_t)(b * 16 + i) * 16 + j) * 512) + dchunk * 128;
        #pragma unroll
        for (int fm = 0; fm < 2; fm++)
          #pragma unroll
          for (int jj = 0; jj < 4; jj++)
            rz[fm][jj] = 1.0f / Z[zb + w1m * 32 + fm * 16 + lg * 4 + jj];
      }
      floatx4 acc1[2][2] = {{zero, zero}, {zero, zero}};
      __syncthreads();                       // prev readers of sKV done
      *(float4*)((char*)sKV + lofsA) = p0a;
      *(float4*)((char*)sKV + lofsB) = p0b;
      // prefetch K cc=64 (lands during GEMM1a)
      float4 p1a = *(const float4*)(kb + krr * 128 + 64 + ksl * 8);
      float4 p1b = *(const float4*)(kb + (krr + 64) * 128 + 64 + ksl * 8);
      __syncthreads();
      for (int kc = 0; kc < 64; kc += 32) {  // GEMM1 over cc=0 half
        half8 ah[2];
        for (int fm = 0; fm < 2; fm++)
          ah[fm] = fragP128(sKV, w1m * 32 + fm * 16 + lr, kc + lg * 8);
        for (int fn = 0; fn < 2; fn++) {
          half8 bh = fragP256(sQ, w1n * 32 + fn * 16 + lr, kc + lg * 8);
          for (int fm = 0; fm < 2; fm++)
            acc1[fm][fn] = MFMA16(ah[fm], bh, acc1[fm][fn]);
        }
      }
      __syncthreads();
      *(float4*)((char*)sKV + lofsA) = p1a;
      *(float4*)((char*)sKV + lofsB) = p1b;
      __syncthreads();
      for (int kc = 0; kc < 64; kc += 32) {  // GEMM1 over cc=64 half
        half8 ah[2];
        for (int fm = 0; fm < 2; fm++)
          ah[fm] = fragP128(sKV, w1m * 32 + fm * 16 + lr, kc + lg * 8);
        for (int fn = 0; fn < 2; fn++) {
          half8 bh = fragP256(sQ, w1n * 32 + fn * 16 + lr, 64 + kc + lg * 8);
          for (int fm = 0; fm < 2; fm++)
            acc1[fm][fn] = MFMA16(ah[fm], bh, acc1[fm][fn]);
        }
      }
      for (int dsub = 0; dsub < 2; dsub++) {
        __syncthreads();   // prev GEMM2 done with E and KV buffers
        if ((wave >> 2) == dsub) {
          // writer waves: E' = exp(S)/Z, packed 4x f16 -> one 8B LDS write
          #pragma unroll
          for (int fm = 0; fm < 2; fm++)
            #pragma unroll
            for (int fn = 0; fn < 2; fn++) {
              int s = w1n * 32 + fn * 16 + lr;
              int ds0 = (w1m & 1) * 32 + fm * 16 + lg * 4;
              union { f16 a[4]; float2 u; } pk;
              #pragma unroll
              for (int jj = 0; jj < 4; jj++)
                pk.a[jj] = (f16)(exp2f(acc1[fm][fn][jj] * RSL2E) * rz[fm][jj]);
              int ofs = ((s << 7) + (ds0 << 1)) ^ ((s & 7) << 4);
              *(float2*)((char*)sE + ofs) = pk.u;
            }
        } else {
          // stager waves: write the V tile prefetched at iteration start
          *(float4*)((char*)sKV + vlofs[0]) = vr_0;
          *(float4*)((char*)sKV + vlofs[1]) = vr_1;
          *(float4*)((char*)sKV + vlofs[2]) = vr_2;
          *(float4*)((char*)sKV + vlofs[3]) = vr_3;
        }
        __syncthreads();
        for (int kc = 0; kc < 64; kc += 32) {
          half8 ah[2];
          for (int fm = 0; fm < 2; fm++)
            ah[fm] = fragP128(sE, w2m * 32 + fm * 16 + lr, kc + lg * 8);
          for (int fn = 0; fn < 2; fn++) {
            half8 bh = fragP128(sKV, w2n * 32 + fn * 16 + lr, kc + lg * 8);
            for (int fm = 0; fm < 2; fm++)
              acc2[fm][fn] = MFMA16(ah[fm], bh, acc2[fm][fn]);
          }
        }
      }
    }
  }
  // epilogue: write f32 partial to Pbuf via LDS for coalescing
  __syncthreads();
  float* ef = (float*)pool;   // [64][128] f32 = 32 KB (overlays sQ+sKV)
  for (int fm = 0; fm < 2; fm++) for (int fn = 0; fn < 2; fn++) {
    int c = w2n * 32 + fn * 16 + lr;
    for (int jj = 0; jj < 4; jj++) {
      int s = w2m * 32 + fm * 16 + lg * 4 + jj;
      ef[s * 128 + c] = acc2[fm][fn][jj];
    }
  }
  __syncthreads();
  float* po = Pbuf + ((size_t)((((b * 16 + i) * 8 + st) * 4) + dq)) * 8192;
  for (int idx = tid; idx < 2048; idx += 512)
    ((float4*)po)[idx] = ((const float4*)ef)[idx];
}

extern "C" void kernel_launch(void* const* d_in, const int* in_sizes, int n_in,
                              void* d_out, int out_size, void* d_ws, size_t ws_size,
                              hipStream_t stream) {
  const float* query     = (const float*)d_in[0];
  const float* key_value = (const float*)d_in[1];
  const float* Wq  = (const float*)d_in[2];
  const float* bq  = (const float*)d_in[3];
  const float* Wkv = (const float*)d_in[4];
  const float* bkv = (const float*)d_in[5];
  const float* Wo  = (const float*)d_in[6];
  const float* bo  = (const float*)d_in[7];
  float* out = (float*)d_out;

  char* ws = (char*)d_ws;
  size_t off = 0;
  auto alloc = [&](size_t bytes) -> char* {
    char* p = ws + off;
    off += (bytes + 255) & ~(size_t)255;
    return p;
  };
  const size_t SZH = (size_t)16384 * 128 * 2;   // one f16 array over all rows
  f16* qhp  = (f16*)alloc(SZH);   // q projected, single f16
  f16* khp  = (f16*)alloc(SZH);   // k projected, single f16
  f16* vT   = (f16*)alloc(SZH);   // v projected, transposed [b][c][l], single f16
  float* Pbuf = (float*)alloc((size_t)1024 * 8192 * 4);   // 33.5 MB partials (4 d-quarters)
  f16* WqTh  = (f16*)alloc(32768); f16* WqTl  = (f16*)alloc(32768);
  f16* WkvTh = (f16*)alloc(65536); f16* WkvTl = (f16*)alloc(65536);
  f16* WoTh  = (f16*)alloc(32768); f16* WoTl  = (f16*)alloc(32768);
  float* Zb = (float*)alloc((size_t)2 * 16 * 16 * 512 * 4);
  float* Ub = (float*)alloc((size_t)2 * 16 * 128 * 4);
  if (off > ws_size) return;   // workspace too small: bail

  k_splitW<<<256, 256, 0, stream>>>(Wq, Wkv, Wo, WqTh, WqTl, WkvTh, WkvTl, WoTh, WoTl);
  // all three projections in one dispatch (q / k / v->vT)
  k_proj<<<768, 512, 0, stream>>>(query, key_value, WqTh, WqTl, WkvTh, WkvTl,
                                  bq, bkv, qhp, khp, vT);
  k_U<<<256, 256, 0, stream>>>(vT, Ub);
  k_passA<<<640, 512, 0, stream>>>(khp, qhp, Zb);
  k_passB<<<1024, 512, 0, stream>>>(qhp, khp, vT, Zb, Pbuf);
  k_final<<<256, 512, 0, stream>>>(Pbuf, Ub, WoTh, WoTl, bo, out);
}

// Round 12
// 112.321 us; speedup vs baseline: 2.2116x; 1.0096x over previous
//
#include <hip/hip_runtime.h>

typedef _Float16 f16;
typedef _Float16 half8 __attribute__((ext_vector_type(8)));
typedef float floatx4 __attribute__((ext_vector_type(4)));

#define MFMA16(a,b,c) __builtin_amdgcn_mfma_f32_16x16x32_f16((a),(b),(c),0,0,0)
// (1/sqrt(128)) * log2(e)
#define RSL2E 0.12751743f

__device__ __forceinline__ void split2(float x, f16 &h, f16 &l) {
  f16 hh = (f16)x;
  h = hh;
  l = (f16)(x - (float)hh);
}

// ---- LDS staging: rows of 64 halves (128B pitch), XOR-swizzled ----
__device__ __forceinline__ void stage_rows64(const f16* __restrict__ g, int gstride,
                                             f16* lds, int rows, int tid, int nthr) {
  int total = rows * 8;
  for (int idx = tid; idx < total; idx += nthr) {
    int row = idx >> 3, slot = idx & 7;
    float4 v = *(const float4*)(g + (size_t)row * gstride + slot * 8);
    int lofs = ((row << 7) + (slot << 4)) ^ ((row & 7) << 4);
    *(float4*)((char*)lds + lofs) = v;
  }
}
// rows of 128 halves (256B pitch), XOR-swizzled
__device__ __forceinline__ void stage_rows128(const f16* __restrict__ g, int gstride,
                                              f16* lds, int rows, int tid, int nthr) {
  int total = rows * 16;
  for (int idx = tid; idx < total; idx += nthr) {
    int row = idx >> 4, slot = idx & 15;
    float4 v = *(const float4*)(g + (size_t)row * gstride + slot * 8);
    int lofs = ((row << 8) + (slot << 4)) ^ ((row & 7) << 4);
    *(float4*)((char*)lds + lofs) = v;
  }
}
// stage fp32 rows with on-the-fly split into h/l tiles (64 cols, 128B pitch each)
__device__ __forceinline__ void stage_split64(const float* __restrict__ g, int gstride,
                                              f16* ldsh, f16* ldsl, int rows,
                                              int tid, int nthr) {
  int total = rows * 16;
  for (int idx = tid; idx < total; idx += nthr) {
    int row = idx >> 4, cg = idx & 15;
    float4 va = *(const float4*)(g + (size_t)row * gstride + cg * 4);
    union { f16 a[4]; uint2 u; } hh, ll;
    split2(va.x, hh.a[0], ll.a[0]);
    split2(va.y, hh.a[1], ll.a[1]);
    split2(va.z, hh.a[2], ll.a[2]);
    split2(va.w, hh.a[3], ll.a[3]);
    int lofs = ((row << 7) + (cg << 3)) ^ ((row & 7) << 4);
    *(uint2*)((char*)ldsh + lofs) = hh.u;
    *(uint2*)((char*)ldsl + lofs) = ll.u;
  }
}
__device__ __forceinline__ half8 fragP128(const f16* lds, int row, int kofs) {
  int ofs = ((row << 7) + (kofs << 1)) ^ ((row & 7) << 4);
  return *(const half8*)((const char*)lds + ofs);
}
__device__ __forceinline__ half8 fragP256(const f16* lds, int row, int kofs) {
  int ofs = ((row << 8) + (kofs << 1)) ^ ((row & 7) << 4);
  return *(const half8*)((const char*)lds + ofs);
}

// ---- transpose + split the three weight matrices ----
__global__ void k_splitW(const float* __restrict__ Wq, const float* __restrict__ Wkv,
                         const float* __restrict__ Wo,
                         f16* WqTh, f16* WqTl, f16* WkvTh, f16* WkvTl,
                         f16* WoTh, f16* WoTl) {
  int idx = blockIdx.x * 256 + threadIdx.x;
  if (idx >= 65536) return;
  float v; f16 *ph, *pl; int dst;
  if (idx < 16384) {
    int n = idx >> 7, c = idx & 127;
    v = Wq[c * 128 + n]; ph = WqTh; pl = WqTl; dst = idx;
  } else if (idx < 49152) {
    int t = idx - 16384; int n = t >> 7, c = t & 127;
    v = Wkv[c * 256 + n]; ph = WkvTh; pl = WkvTl; dst = t;
  } else {
    int t = idx - 49152; int n = t >> 7, c = t & 127;
    v = Wo[c * 128 + n]; ph = WoTh; pl = WoTl; dst = t;
  }
  f16 h, l; split2(v, h, l);
  ph[dst] = h; pl[dst] = l;
}

// ---- fused split+GEMM for all three projections in ONE dispatch (grid 768) ----
__global__ __launch_bounds__(512, 2)
void k_proj(const float* __restrict__ query, const float* __restrict__ key_value,
            const f16* __restrict__ WqTh, const f16* __restrict__ WqTl,
            const f16* __restrict__ WkvTh, const f16* __restrict__ WkvTl,
            const float* __restrict__ bq, const float* __restrict__ bkv,
            f16* __restrict__ qhp, f16* __restrict__ khp, f16* __restrict__ vT) {
  int pidx = blockIdx.x >> 8, blk = blockIdx.x & 255;
  const float* A; const f16 *BTh, *BTl; const float* bias; f16* out; int mode;
  if (pidx == 0)      { A = query;     BTh = WqTh;          BTl = WqTl;          bias = bq;        out = qhp; mode = 0; }
  else if (pidx == 1) { A = key_value; BTh = WkvTh;         BTl = WkvTl;         bias = bkv;       out = khp; mode = 0; }
  else                { A = key_value; BTh = WkvTh + 16384; BTl = WkvTl + 16384; bias = bkv + 128; out = vT;  mode = 1; }
  __shared__ f16 pool[24576];
  f16* sAh = pool;           // [64][64]
  f16* sAl = pool + 4096;
  f16* sBh = pool + 8192;    // [128][64]
  f16* sBl = pool + 16384;
  int tid = threadIdx.x, wave = tid >> 6, lane = tid & 63, lg = lane >> 4, lr = lane & 15;
  int wm = wave >> 2, wn = wave & 3;   // 2 x 4 waves, 32x32 wave tiles
  size_t rowbase = (size_t)blk * 64;
  floatx4 zero = {0.f, 0.f, 0.f, 0.f};
  floatx4 acc[2][2] = {{zero, zero}, {zero, zero}};
  for (int cc = 0; cc < 128; cc += 64) {
    __syncthreads();
    stage_split64(A + rowbase * 128 + cc, 128, sAh, sAl, 64, tid, 512);
    stage_rows64(BTh + cc, 128, sBh, 128, tid, 512);
    stage_rows64(BTl + cc, 128, sBl, 128, tid, 512);
    __syncthreads();
    for (int kc = 0; kc < 64; kc += 32) {
      half8 ah[2], al[2];
      for (int fm = 0; fm < 2; fm++) {
        ah[fm] = fragP128(sAh, wm * 32 + fm * 16 + lr, kc + lg * 8);
        al[fm] = fragP128(sAl, wm * 32 + fm * 16 + lr, kc + lg * 8);
      }
      for (int fn = 0; fn < 2; fn++) {
        half8 bh = fragP128(sBh, wn * 32 + fn * 16 + lr, kc + lg * 8);
        half8 bl = fragP128(sBl, wn * 32 + fn * 16 + lr, kc + lg * 8);
        for (int fm = 0; fm < 2; fm++) {
          acc[fm][fn] = MFMA16(ah[fm], bh, acc[fm][fn]);
          acc[fm][fn] = MFMA16(ah[fm], bl, acc[fm][fn]);
          acc[fm][fn] = MFMA16(al[fm], bh, acc[fm][fn]);
        }
      }
    }
  }
  __syncthreads();
  f16* e = pool;          // [64][136] padded, single
  for (int fm = 0; fm < 2; fm++) for (int fn = 0; fn < 2; fn++) {
    int n = wn * 32 + fn * 16 + lr;
    float bs = bias[n];
    for (int jj = 0; jj < 4; jj++) {
      int m = wm * 32 + fm * 16 + lg * 4 + jj;
      e[m * 136 + n] = (f16)(acc[fm][fn][jj] + bs);
    }
  }
  __syncthreads();
  if (mode == 0) {
    for (int idx = tid; idx < 1024; idx += 512) {
      int r = idx >> 4, sl = idx & 15;
      *(float4*)(out + (rowbase + r) * 128 + sl * 8) =
          *(const float4*)((const char*)e + r * 272 + sl * 16);
    }
  } else {
    size_t bidx = rowbase >> 13, lofs = rowbase & 8191;
    for (int idx = tid; idx < 1024; idx += 512) {
      int c = idx >> 3, sl = idx & 7;
      union { f16 a[8]; float4 v; } th;
      for (int t = 0; t < 8; t++) th.a[t] = e[(sl * 8 + t) * 136 + c];
      *(float4*)(out + (bidx * 128 + c) * 8192 + lofs + sl * 8) = th.v;
    }
  }
}

// ---- fused reduce+final projection: out fp32 = (P0+P1+P2+P3+U) * WoT^T + bo ----
__global__ __launch_bounds__(512, 2)
void k_final(const float* __restrict__ Pbuf, const float* __restrict__ U,
             const f16* __restrict__ BTh, const f16* __restrict__ BTl,
             const float* __restrict__ bias, float* __restrict__ out) {
  __shared__ f16 pool[24576];
  f16* sAh = pool;
  f16* sAl = pool + 4096;
  f16* sBh = pool + 8192;
  f16* sBl = pool + 16384;
  int tid = threadIdx.x, wave = tid >> 6, lane = tid & 63, lg = lane >> 4, lr = lane & 15;
  int wm = wave >> 2, wn = wave & 3;
  size_t rowbase = (size_t)blockIdx.x * 64;
  int b = (int)(rowbase >> 13), r0 = (int)(rowbase & 8191);
  int i = r0 >> 9, st = (r0 >> 6) & 7;
  const float* p0 = Pbuf + ((size_t)(((b * 16 + i) * 8 + st) * 4)) * 8192;
  const float* p1 = p0 + 8192;
  const float* p2 = p0 + 16384;
  const float* p3 = p0 + 24576;
  const float* Ub = U + ((size_t)b * 16 + i) * 128;
  floatx4 zero = {0.f, 0.f, 0.f, 0.f};
  floatx4 acc[2][2] = {{zero, zero}, {zero, zero}};
  for (int cc = 0; cc < 128; cc += 64) {
    __syncthreads();
    for (int idx = tid; idx < 1024; idx += 512) {
      int row = idx >> 4, cg = idx & 15;
      int c = cc + cg * 4;
      float4 a0 = *(const float4*)(p0 + row * 128 + c);
      float4 a1 = *(const float4*)(p1 + row * 128 + c);
      float4 a2 = *(const float4*)(p2 + row * 128 + c);
      float4 a3 = *(const float4*)(p3 + row * 128 + c);
      float4 uu = *(const float4*)(Ub + c);
      float vals[4] = {(a0.x + a1.x) + (a2.x + a3.x) + uu.x,
                       (a0.y + a1.y) + (a2.y + a3.y) + uu.y,
                       (a0.z + a1.z) + (a2.z + a3.z) + uu.z,
                       (a0.w + a1.w) + (a2.w + a3.w) + uu.w};
      union { f16 a[4]; uint2 u; } hh, ll;
      for (int t = 0; t < 4; t++) split2(vals[t], hh.a[t], ll.a[t]);
      int lofs = ((row << 7) + (cg << 3)) ^ ((row & 7) << 4);
      *(uint2*)((char*)sAh + lofs) = hh.u;
      *(uint2*)((char*)sAl + lofs) = ll.u;
    }
    stage_rows64(BTh + cc, 128, sBh, 128, tid, 512);
    stage_rows64(BTl + cc, 128, sBl, 128, tid, 512);
    __syncthreads();
    for (int kc = 0; kc < 64; kc += 32) {
      half8 ah[2], al[2];
      for (int fm = 0; fm < 2; fm++) {
        ah[fm] = fragP128(sAh, wm * 32 + fm * 16 + lr, kc + lg * 8);
        al[fm] = fragP128(sAl, wm * 32 + fm * 16 + lr, kc + lg * 8);
      }
      for (int fn = 0; fn < 2; fn++) {
        half8 bh = fragP128(sBh, wn * 32 + fn * 16 + lr, kc + lg * 8);
        half8 bl = fragP128(sBl, wn * 32 + fn * 16 + lr, kc + lg * 8);
        for (int fm = 0; fm < 2; fm++) {
          acc[fm][fn] = MFMA16(ah[fm], bh, acc[fm][fn]);
          acc[fm][fn] = MFMA16(ah[fm], bl, acc[fm][fn]);
          acc[fm][fn] = MFMA16(al[fm], bh, acc[fm][fn]);
        }
      }
    }
  }
  __syncthreads();
  float* ef = (float*)pool;   // [64][132] padded fp32
  for (int fm = 0; fm < 2; fm++) for (int fn = 0; fn < 2; fn++) {
    int n = wn * 32 + fn * 16 + lr;
    float bs = bias[n];
    for (int jj = 0; jj < 4; jj++) {
      int m = wm * 32 + fm * 16 + lg * 4 + jj;
      ef[m * 132 + n] = acc[fm][fn][jj] + bs;
    }
  }
  __syncthreads();
  for (int idx = tid; idx < 2048; idx += 512) {
    int r = idx >> 5, sl = idx & 31;
    *(float4*)(out + (rowbase + r) * 128 + sl * 4) = *(const float4*)(ef + r * 132 + sl * 4);
  }
}

// ---- U[b][i][c] = (1/512) * sum over disallowed k-blocks of their column sums of v ----
__global__ void k_U(const f16* __restrict__ vT, float* __restrict__ U) {
  int b = blockIdx.x >> 7, c = blockIdx.x & 127;
  int tid = threadIdx.x;
  const f16* r = vT + ((size_t)b * 128 + c) * 8192;
  float s = 0.f;
  const float4* r4 = (const float4*)(r + tid * 32);
  for (int t = 0; t < 4; t++) {
    float4 v = r4[t];
    const f16* a = (const f16*)&v;
    for (int u = 0; u < 8; u++) s += (float)a[u];
  }
  __shared__ float part[256];
  __shared__ float bs[16];
  part[tid] = s;
  __syncthreads();
  if (tid < 16) {
    float t = 0.f;
    for (int u = 0; u < 16; u++) t += part[tid * 16 + u];
    bs[tid] = t;
  }
  __syncthreads();
  if (tid < 16) {
    int i = tid;
    float tot = 0.f;
    for (int j = 0; j < 16; j++) tot += bs[j];
    int j0 = i - 2 < 0 ? 0 : i - 2;
    int j1 = i + 2 > 15 ? 15 : i + 2;
    float win = 0.f;
    for (int j = j0; j <= j1; j++) win += bs[j];
    U[((size_t)b * 16 + i) * 128 + c] = (tot - win) * (1.0f / 512.0f);
  }
}

// ---- pass A: Z[b][i][j][d] = sum_s exp2(RSL2E * (k_d . q_s)), single f16 inputs ----
__global__ __launch_bounds__(512, 4)
void k_passA(const f16* __restrict__ kp, const f16* __restrict__ qp,
             float* __restrict__ Z) {
  int bid = blockIdx.x;
  int wg = (bid & 7) * 80 + (bid >> 3);     // XCD-aware bijective swizzle (640 = 8*80)
  int dchunk = wg & 3; int rest = wg >> 2;
  int slot = rest % 5; int rest2 = rest / 5;
  int i = rest2 & 15; int b = rest2 >> 4;
  int j = i - 2 + slot;
  if (j < 0 || j > 15) return;
  __shared__ f16 sK[16384], sQ[16384];  // 64 KiB -> 2 WG/CU
  int tid = threadIdx.x, wave = tid >> 6, lane = tid & 63, lg = lane >> 4, lr = lane & 15;
  int wm = wave >> 1, wn = wave & 1;   // 4 x 2 waves; wave tile 32(d) x 64(s)
  size_t krow = (size_t)b * 8192 + j * 512 + dchunk * 128;
  stage_rows128(kp + krow * 128, 128, sK, 128, tid, 512);
  float zp[2][4] = {{0.f,0.f,0.f,0.f},{0.f,0.f,0.f,0.f}};
  floatx4 zero = {0.f, 0.f, 0.f, 0.f};
  for (int sc = 0; sc < 4; sc++) {
    __syncthreads();
    size_t qrow = (size_t)b * 8192 + i * 512 + sc * 128;
    stage_rows128(qp + qrow * 128, 128, sQ, 128, tid, 512);
    __syncthreads();
    floatx4 acc[2][4] = {{zero,zero,zero,zero},{zero,zero,zero,zero}};
    for (int kc = 0; kc < 128; kc += 32) {
      half8 ah[2];
      for (int fm = 0; fm < 2; fm++)
        ah[fm] = fragP256(sK, wm * 32 + fm * 16 + lr, kc + lg * 8);
      for (int fn = 0; fn < 4; fn++) {
        half8 bh = fragP256(sQ, wn * 64 + fn * 16 + lr, kc + lg * 8);
        for (int fm = 0; fm < 2; fm++)
          acc[fm][fn] = MFMA16(ah[fm], bh, acc[fm][fn]);
      }
    }
    for (int fm = 0; fm < 2; fm++) for (int fn = 0; fn < 4; fn++)
      for (int jj = 0; jj < 4; jj++)
        zp[fm][jj] += exp2f(acc[fm][fn][jj] * RSL2E);
  }
  // in-wave butterfly over lr (16 s-columns)
  for (int off = 1; off < 16; off <<= 1)
    for (int fm = 0; fm < 2; fm++) for (int jj = 0; jj < 4; jj++)
      zp[fm][jj] += __shfl_xor(zp[fm][jj], off, 64);
  // cross-wave combine of the two wn halves via LDS
  __syncthreads();
  float* sred = (float*)sQ;      // 256 floats
  if (lr == 0) {
    for (int fm = 0; fm < 2; fm++) for (int jj = 0; jj < 4; jj++) {
      int d = wm * 32 + fm * 16 + lg * 4 + jj;
      sred[wn * 128 + d] = zp[fm][jj];
    }
  }
  __syncthreads();
  if (tid < 128) {
    size_t zb = (((size_t)(b * 16 + i) * 16 + j) * 512) + dchunk * 128;
    Z[zb + tid] = sred[tid] + sred[128 + tid];
  }
}

// ---- pass B v4: full-width tiles, 4 barriers/iter, all-wave E write ----
// per (b, i, s-tile of 64, d-quarter of 128): partial PV into Pbuf (f32); 64 KB LDS
__global__ __launch_bounds__(512, 4)
void k_passB(const f16* __restrict__ qp, const f16* __restrict__ kp,
             const f16* __restrict__ vT,
             const float* __restrict__ Z, float* __restrict__ Pbuf) {
  int bid = blockIdx.x;
  int wg = ((bid & 7) << 7) | (bid >> 3);   // XCD-aware bijective swizzle (1024 = 8*128)
  int dq = wg & 3, st = (wg >> 2) & 7, i = (wg >> 5) & 15, b = wg >> 9;
  __shared__ __align__(16) char pool[65536];
  f16* sQ  = (f16*)pool;              // [64 s][128 c], 256B pitch, 16 KB
  f16* sKV = (f16*)(pool + 16384);    // [128][128], 256B pitch, 32 KB: K tile, then V tile
  f16* sE  = (f16*)(pool + 49152);    // [64 s][128 d], 256B pitch, 16 KB
  int tid = threadIdx.x, wave = tid >> 6, lane = tid & 63, lg = lane >> 4, lr = lane & 15;
  int w1m = wave >> 1, w1n = wave & 1;    // GEMM1: 4(d) x 2(s)
  int w2m = wave >> 2, w2n = wave & 3;    // GEMM2: 2(s) x 4(c)
  // staging duty for 256B-pitch [128][128] tiles: 4 rows per thread
  int srow = tid >> 4, sslot = tid & 15;
  int sl0 = (((srow      ) << 8) + (sslot << 4)) ^ ((srow & 7) << 4);
  int sl1 = (((srow +  32) << 8) + (sslot << 4)) ^ ((srow & 7) << 4);
  int sl2 = (((srow +  64) << 8) + (sslot << 4)) ^ ((srow & 7) << 4);
  int sl3 = (((srow +  96) << 8) + (sslot << 4)) ^ ((srow & 7) << 4);
  size_t qrow = (size_t)b * 8192 + i * 512 + st * 64;
  stage_rows128(qp + qrow * 128, 128, sQ, 64, tid, 512);
  floatx4 zero = {0.f, 0.f, 0.f, 0.f};
  floatx4 acc2[2][2] = {{zero, zero}, {zero, zero}};
  const f16* vbase = vT + (size_t)b * 1048576;
  for (int slot = 0; slot < 5; slot++) {
    int j = i - 2 + slot;
    if (j < 0 || j > 15) continue;
    // ---- iteration-start prefetches ----
    const f16* kb = kp + ((size_t)b * 8192 + j * 512 + dq * 128) * 128;
    float4 k0 = *(const float4*)(kb + (size_t)(srow      ) * 128 + sslot * 8);
    float4 k1 = *(const float4*)(kb + (size_t)(srow +  32) * 128 + sslot * 8);
    float4 k2 = *(const float4*)(kb + (size_t)(srow +  64) * 128 + sslot * 8);
    float4 k3 = *(const float4*)(kb + (size_t)(srow +  96) * 128 + sslot * 8);
    const f16* gv = vbase + (size_t)j * 512 + dq * 128;
    float4 v0 = *(const float4*)(gv + (size_t)(srow      ) * 8192 + sslot * 8);
    float4 v1 = *(const float4*)(gv + (size_t)(srow +  32) * 8192 + sslot * 8);
    float4 v2 = *(const float4*)(gv + (size_t)(srow +  64) * 8192 + sslot * 8);
    float4 v3 = *(const float4*)(gv + (size_t)(srow +  96) * 8192 + sslot * 8);
    float rz[2][4];
    {
      size_t zb = (((size_t)(b * 16 + i) * 16 + j) * 512) + dq * 128;
      #pragma unroll
      for (int fm = 0; fm < 2; fm++)
        #pragma unroll
        for (int jj = 0; jj < 4; jj++)
          rz[fm][jj] = 1.0f / Z[zb + w1m * 32 + fm * 16 + lg * 4 + jj];
    }
    __syncthreads();                 // B1: prev GEMM2 done reading sKV(V)/sE
    *(float4*)((char*)sKV + sl0) = k0;
    *(float4*)((char*)sKV + sl1) = k1;
    *(float4*)((char*)sKV + sl2) = k2;
    *(float4*)((char*)sKV + sl3) = k3;
    __syncthreads();                 // B2: K tile staged
    // GEMM1: S^T[d][s], full c=128 contraction (16 MFMA/wave)
    floatx4 acc1[2][2] = {{zero, zero}, {zero, zero}};
    #pragma unroll
    for (int kc = 0; kc < 128; kc += 32) {
      half8 ah0 = fragP256(sKV, w1m * 32 + lr, kc + lg * 8);
      half8 ah1 = fragP256(sKV, w1m * 32 + 16 + lr, kc + lg * 8);
      #pragma unroll
      for (int fn = 0; fn < 2; fn++) {
        half8 bq = fragP256(sQ, w1n * 32 + fn * 16 + lr, kc + lg * 8);
        acc1[0][fn] = MFMA16(ah0, bq, acc1[0][fn]);
        acc1[1][fn] = MFMA16(ah1, bq, acc1[1][fn]);
      }
    }
    __syncthreads();                 // B3: GEMM1 reads of sKV done
    // all waves: write E' quadrant (packed 4x f16 -> 8B) + stage V tile
    #pragma unroll
    for (int fm = 0; fm < 2; fm++)
      #pragma unroll
      for (int fn = 0; fn < 2; fn++) {
        int s = w1n * 32 + fn * 16 + lr;
        int d0 = w1m * 32 + fm * 16 + lg * 4;
        union { f16 a[4]; float2 u; } pk;
        #pragma unroll
        for (int jj = 0; jj < 4; jj++)
          pk.a[jj] = (f16)(exp2f(acc1[fm][fn][jj] * RSL2E) * rz[fm][jj]);
        int ofs = ((s << 8) + (d0 << 1)) ^ ((s & 7) << 4);
        *(float2*)((char*)sE + ofs) = pk.u;
      }
    *(float4*)((char*)sKV + sl0) = v0;
    *(float4*)((char*)sKV + sl1) = v1;
    *(float4*)((char*)sKV + sl2) = v2;
    *(float4*)((char*)sKV + sl3) = v3;
    __syncthreads();                 // B4: E + V staged
    // GEMM2: out[s][c] partial over this iter's 128 d (16 MFMA/wave)
    #pragma unroll
    for (int kc = 0; kc < 128; kc += 32) {
      half8 ea0 = fragP256(sE, w2m * 32 + lr, kc + lg * 8);
      half8 ea1 = fragP256(sE, w2m * 32 + 16 + lr, kc + lg * 8);
      #pragma unroll
      for (int fn = 0; fn < 2; fn++) {
        half8 bh = fragP256(sKV, w2n * 32 + fn * 16 + lr, kc + lg * 8);
        acc2[0][fn] = MFMA16(ea0, bh, acc2[0][fn]);
        acc2[1][fn] = MFMA16(ea1, bh, acc2[1][fn]);
      }
    }
  }
  // epilogue: write f32 partial to Pbuf via LDS for coalescing
  __syncthreads();
  float* ef = (float*)pool;   // [64][128] f32 = 32 KB (overlays sQ + half of sKV)
  for (int fm = 0; fm < 2; fm++) for (int fn = 0; fn < 2; fn++) {
    int c = w2n * 32 + fn * 16 + lr;
    for (int jj = 0; jj < 4; jj++) {
      int s = w2m * 32 + fm * 16 + lg * 4 + jj;
      ef[s * 128 + c] = acc2[fm][fn][jj];
    }
  }
  __syncthreads();
  float* po = Pbuf + ((size_t)((((b * 16 + i) * 8 + st) * 4) + dq)) * 8192;
  for (int idx = tid; idx < 2048; idx += 512)
    ((float4*)po)[idx] = ((const float4*)ef)[idx];
}

extern "C" void kernel_launch(void* const* d_in, const int* in_sizes, int n_in,
                              void* d_out, int out_size, void* d_ws, size_t ws_size,
                              hipStream_t stream) {
  const float* query     = (const float*)d_in[0];
  const float* key_value = (const float*)d_in[1];
  const float* Wq  = (const float*)d_in[2];
  const float* bq  = (const float*)d_in[3];
  const float* Wkv = (const float*)d_in[4];
  const float* bkv = (const float*)d_in[5];
  const float* Wo  = (const float*)d_in[6];
  const float* bo  = (const float*)d_in[7];
  float* out = (float*)d_out;

  char* ws = (char*)d_ws;
  size_t off = 0;
  auto alloc = [&](size_t bytes) -> char* {
    char* p = ws + off;
    off += (bytes + 255) & ~(size_t)255;
    return p;
  };
  const size_t SZH = (size_t)16384 * 128 * 2;   // one f16 array over all rows
  f16* qhp  = (f16*)alloc(SZH);   // q projected, single f16
  f16* khp  = (f16*)alloc(SZH);   // k projected, single f16
  f16* vT   = (f16*)alloc(SZH);   // v projected, transposed [b][c][l], single f16
  float* Pbuf = (float*)alloc((size_t)1024 * 8192 * 4);   // 33.5 MB partials (4 d-quarters)
  f16* WqTh  = (f16*)alloc(32768); f16* WqTl  = (f16*)alloc(32768);
  f16* WkvTh = (f16*)alloc(65536); f16* WkvTl = (f16*)alloc(65536);
  f16* WoTh  = (f16*)alloc(32768); f16* WoTl  = (f16*)alloc(32768);
  float* Zb = (float*)alloc((size_t)2 * 16 * 16 * 512 * 4);
  float* Ub = (float*)alloc((size_t)2 * 16 * 128 * 4);
  if (off > ws_size) return;   // workspace too small: bail

  k_splitW<<<256, 256, 0, stream>>>(Wq, Wkv, Wo, WqTh, WqTl, WkvTh, WkvTl, WoTh, WoTl);
  // all three projections in one dispatch (q / k / v->vT)
  k_proj<<<768, 512, 0, stream>>>(query, key_value, WqTh, WqTl, WkvTh, WkvTl,
                                  bq, bkv, qhp, khp, vT);
  k_U<<<256, 256, 0, stream>>>(vT, Ub);
  k_passA<<<640, 512, 0, stream>>>(khp, qhp, Zb);
  k_passB<<<1024, 512, 0, stream>>>(qhp, khp, vT, Zb, Pbuf);
  k_final<<<256, 512, 0, stream>>>(Pbuf, Ub, WoTh, WoTl, bo, out);
}

// Round 13
// 106.157 us; speedup vs baseline: 2.3401x; 1.0581x over previous
//
#include <hip/hip_runtime.h>

typedef _Float16 f16;
typedef _Float16 half8 __attribute__((ext_vector_type(8)));
typedef float floatx4 __attribute__((ext_vector_type(4)));

#define MFMA16(a,b,c) __builtin_amdgcn_mfma_f32_16x16x32_f16((a),(b),(c),0,0,0)
// (1/sqrt(128)) * log2(e)
#define RSL2E 0.12751743f

__device__ __forceinline__ void split2(float x, f16 &h, f16 &l) {
  f16 hh = (f16)x;
  h = hh;
  l = (f16)(x - (float)hh);
}

// ---- LDS staging: rows of 64 halves (128B pitch), XOR-swizzled ----
__device__ __forceinline__ void stage_rows64(const f16* __restrict__ g, int gstride,
                                             f16* lds, int rows, int tid, int nthr) {
  int total = rows * 8;
  for (int idx = tid; idx < total; idx += nthr) {
    int row = idx >> 3, slot = idx & 7;
    float4 v = *(const float4*)(g + (size_t)row * gstride + slot * 8);
    int lofs = ((row << 7) + (slot << 4)) ^ ((row & 7) << 4);
    *(float4*)((char*)lds + lofs) = v;
  }
}
// rows of 128 halves (256B pitch), XOR-swizzled
__device__ __forceinline__ void stage_rows128(const f16* __restrict__ g, int gstride,
                                              f16* lds, int rows, int tid, int nthr) {
  int total = rows * 16;
  for (int idx = tid; idx < total; idx += nthr) {
    int row = idx >> 4, slot = idx & 15;
    float4 v = *(const float4*)(g + (size_t)row * gstride + slot * 8);
    int lofs = ((row << 8) + (slot << 4)) ^ ((row & 7) << 4);
    *(float4*)((char*)lds + lofs) = v;
  }
}
__device__ __forceinline__ half8 fragP128(const f16* lds, int row, int kofs) {
  int ofs = ((row << 7) + (kofs << 1)) ^ ((row & 7) << 4);
  return *(const half8*)((const char*)lds + ofs);
}
__device__ __forceinline__ half8 fragP256(const f16* lds, int row, int kofs) {
  int ofs = ((row << 8) + (kofs << 1)) ^ ((row & 7) << 4);
  return *(const half8*)((const char*)lds + ofs);
}
// pack a float4 into split h/l uint2 pairs
__device__ __forceinline__ void pack_split(float4 v, uint2 &h, uint2 &l) {
  union { f16 a[4]; uint2 u; } hh, ll;
  split2(v.x, hh.a[0], ll.a[0]);
  split2(v.y, hh.a[1], ll.a[1]);
  split2(v.z, hh.a[2], ll.a[2]);
  split2(v.w, hh.a[3], ll.a[3]);
  h = hh.u; l = ll.u;
}

// ---- transpose + split the three weight matrices ----
__global__ void k_splitW(const float* __restrict__ Wq, const float* __restrict__ Wkv,
                         const float* __restrict__ Wo,
                         f16* WqTh, f16* WqTl, f16* WkvTh, f16* WkvTl,
                         f16* WoTh, f16* WoTl) {
  int idx = blockIdx.x * 256 + threadIdx.x;
  if (idx >= 65536) return;
  float v; f16 *ph, *pl; int dst;
  if (idx < 16384) {
    int n = idx >> 7, c = idx & 127;
    v = Wq[c * 128 + n]; ph = WqTh; pl = WqTl; dst = idx;
  } else if (idx < 49152) {
    int t = idx - 16384; int n = t >> 7, c = t & 127;
    v = Wkv[c * 256 + n]; ph = WkvTh; pl = WkvTl; dst = t;
  } else {
    int t = idx - 49152; int n = t >> 7, c = t & 127;
    v = Wo[c * 128 + n]; ph = WoTh; pl = WoTl; dst = t;
  }
  f16 h, l; split2(v, h, l);
  ph[dst] = h; pl[dst] = l;
}

// ---- fused split+GEMM for all three projections in ONE dispatch (grid 768) ----
// with register prefetch of the cc=64 staging inputs (R11 technique)
__global__ __launch_bounds__(512, 2)
void k_proj(const float* __restrict__ query, const float* __restrict__ key_value,
            const f16* __restrict__ WqTh, const f16* __restrict__ WqTl,
            const f16* __restrict__ WkvTh, const f16* __restrict__ WkvTl,
            const float* __restrict__ bq, const float* __restrict__ bkv,
            f16* __restrict__ qhp, f16* __restrict__ khp, f16* __restrict__ vT) {
  int pidx = blockIdx.x >> 8, blk = blockIdx.x & 255;
  const float* A; const f16 *BTh, *BTl; const float* bias; f16* out; int mode;
  if (pidx == 0)      { A = query;     BTh = WqTh;          BTl = WqTl;          bias = bq;        out = qhp; mode = 0; }
  else if (pidx == 1) { A = key_value; BTh = WkvTh;         BTl = WkvTl;         bias = bkv;       out = khp; mode = 0; }
  else                { A = key_value; BTh = WkvTh + 16384; BTl = WkvTl + 16384; bias = bkv + 128; out = vT;  mode = 1; }
  __shared__ f16 pool[24576];
  f16* sAh = pool;           // [64][64]
  f16* sAl = pool + 4096;
  f16* sBh = pool + 8192;    // [128][64]
  f16* sBl = pool + 16384;
  int tid = threadIdx.x, wave = tid >> 6, lane = tid & 63, lg = lane >> 4, lr = lane & 15;
  int wm = wave >> 2, wn = wave & 3;   // 2 x 4 waves, 32x32 wave tiles
  size_t rowbase = (size_t)blk * 64;
  // staging duties
  int arow = tid >> 4, acg = tid & 15;   // A rows arow, arow+32 (fp32, split on write)
  int al0 = ((arow << 7) + (acg << 3)) ^ ((arow & 7) << 4);
  int al1 = (((arow + 32) << 7) + (acg << 3)) ^ ((arow & 7) << 4);
  int brow = tid >> 3, bslot = tid & 7;  // B rows brow, brow+64
  int bl0 = ((brow << 7) + (bslot << 4)) ^ ((brow & 7) << 4);
  int bl1 = (((brow + 64) << 7) + (bslot << 4)) ^ ((brow & 7) << 4);
  const float* Ab = A + rowbase * 128;
  // prefetch cc=0 inputs
  float4 a0 = *(const float4*)(Ab + (size_t)arow * 128 + acg * 4);
  float4 a1 = *(const float4*)(Ab + (size_t)(arow + 32) * 128 + acg * 4);
  float4 b0h = *(const float4*)(BTh + brow * 128 + bslot * 8);
  float4 b1h = *(const float4*)(BTh + (brow + 64) * 128 + bslot * 8);
  float4 b0l = *(const float4*)(BTl + brow * 128 + bslot * 8);
  float4 b1l = *(const float4*)(BTl + (brow + 64) * 128 + bslot * 8);
  floatx4 zero = {0.f, 0.f, 0.f, 0.f};
  floatx4 acc[2][2] = {{zero, zero}, {zero, zero}};
  #pragma unroll
  for (int cc = 0; cc < 128; cc += 64) {
    __syncthreads();
    {
      uint2 h, l;
      pack_split(a0, h, l);
      *(uint2*)((char*)sAh + al0) = h; *(uint2*)((char*)sAl + al0) = l;
      pack_split(a1, h, l);
      *(uint2*)((char*)sAh + al1) = h; *(uint2*)((char*)sAl + al1) = l;
    }
    *(float4*)((char*)sBh + bl0) = b0h;
    *(float4*)((char*)sBh + bl1) = b1h;
    *(float4*)((char*)sBl + bl0) = b0l;
    *(float4*)((char*)sBl + bl1) = b1l;
    __syncthreads();
    if (cc == 0) {   // prefetch cc=64 inputs during compute
      a0 = *(const float4*)(Ab + (size_t)arow * 128 + 64 + acg * 4);
      a1 = *(const float4*)(Ab + (size_t)(arow + 32) * 128 + 64 + acg * 4);
      b0h = *(const float4*)(BTh + 64 + brow * 128 + bslot * 8);
      b1h = *(const float4*)(BTh + 64 + (brow + 64) * 128 + bslot * 8);
      b0l = *(const float4*)(BTl + 64 + brow * 128 + bslot * 8);
      b1l = *(const float4*)(BTl + 64 + (brow + 64) * 128 + bslot * 8);
    }
    #pragma unroll
    for (int kc = 0; kc < 64; kc += 32) {
      half8 ah[2], al[2];
      for (int fm = 0; fm < 2; fm++) {
        ah[fm] = fragP128(sAh, wm * 32 + fm * 16 + lr, kc + lg * 8);
        al[fm] = fragP128(sAl, wm * 32 + fm * 16 + lr, kc + lg * 8);
      }
      for (int fn = 0; fn < 2; fn++) {
        half8 bh = fragP128(sBh, wn * 32 + fn * 16 + lr, kc + lg * 8);
        half8 bl = fragP128(sBl, wn * 32 + fn * 16 + lr, kc + lg * 8);
        for (int fm = 0; fm < 2; fm++) {
          acc[fm][fn] = MFMA16(ah[fm], bh, acc[fm][fn]);
          acc[fm][fn] = MFMA16(ah[fm], bl, acc[fm][fn]);
          acc[fm][fn] = MFMA16(al[fm], bh, acc[fm][fn]);
        }
      }
    }
  }
  __syncthreads();
  f16* e = pool;          // [64][136] padded, single
  for (int fm = 0; fm < 2; fm++) for (int fn = 0; fn < 2; fn++) {
    int n = wn * 32 + fn * 16 + lr;
    float bs = bias[n];
    for (int jj = 0; jj < 4; jj++) {
      int m = wm * 32 + fm * 16 + lg * 4 + jj;
      e[m * 136 + n] = (f16)(acc[fm][fn][jj] + bs);
    }
  }
  __syncthreads();
  if (mode == 0) {
    for (int idx = tid; idx < 1024; idx += 512) {
      int r = idx >> 4, sl = idx & 15;
      *(float4*)(out + (rowbase + r) * 128 + sl * 8) =
          *(const float4*)((const char*)e + r * 272 + sl * 16);
    }
  } else {
    size_t bidx = rowbase >> 13, lofs = rowbase & 8191;
    for (int idx = tid; idx < 1024; idx += 512) {
      int c = idx >> 3, sl = idx & 7;
      union { f16 a[8]; float4 v; } th;
      for (int t = 0; t < 8; t++) th.a[t] = e[(sl * 8 + t) * 136 + c];
      *(float4*)(out + (bidx * 128 + c) * 8192 + lofs + sl * 8) = th.v;
    }
  }
}

// ---- fused reduce+final projection: out fp32 = (P0+P1+P2+P3+U) * WoT^T + bo ----
// with register prefetch of the cc=64 staging inputs
__global__ __launch_bounds__(512, 2)
void k_final(const float* __restrict__ Pbuf, const float* __restrict__ U,
             const f16* __restrict__ BTh, const f16* __restrict__ BTl,
             const float* __restrict__ bias, float* __restrict__ out) {
  __shared__ f16 pool[24576];
  f16* sAh = pool;
  f16* sAl = pool + 4096;
  f16* sBh = pool + 8192;
  f16* sBl = pool + 16384;
  int tid = threadIdx.x, wave = tid >> 6, lane = tid & 63, lg = lane >> 4, lr = lane & 15;
  int wm = wave >> 2, wn = wave & 3;
  size_t rowbase = (size_t)blockIdx.x * 64;
  int b = (int)(rowbase >> 13), r0 = (int)(rowbase & 8191);
  int i = r0 >> 9, st = (r0 >> 6) & 7;
  const float* p0 = Pbuf + ((size_t)(((b * 16 + i) * 8 + st) * 4)) * 8192;
  const float* p1 = p0 + 8192;
  const float* p2 = p0 + 16384;
  const float* p3 = p0 + 24576;
  const float* Ub = U + ((size_t)b * 16 + i) * 128;
  // staging duties
  int arow = tid >> 4, acg = tid & 15;   // A rows arow, arow+32
  int al0 = ((arow << 7) + (acg << 3)) ^ ((arow & 7) << 4);
  int al1 = (((arow + 32) << 7) + (acg << 3)) ^ ((arow & 7) << 4);
  int brow = tid >> 3, bslot = tid & 7;
  int bl0 = ((brow << 7) + (bslot << 4)) ^ ((brow & 7) << 4);
  int bl1 = (((brow + 64) << 7) + (bslot << 4)) ^ ((brow & 7) << 4);
  // prefetch cc=0 inputs
  int c0 = acg * 4;
  float4 r0a0 = *(const float4*)(p0 + arow * 128 + c0);
  float4 r0a1 = *(const float4*)(p1 + arow * 128 + c0);
  float4 r0a2 = *(const float4*)(p2 + arow * 128 + c0);
  float4 r0a3 = *(const float4*)(p3 + arow * 128 + c0);
  float4 r1a0 = *(const float4*)(p0 + (arow + 32) * 128 + c0);
  float4 r1a1 = *(const float4*)(p1 + (arow + 32) * 128 + c0);
  float4 r1a2 = *(const float4*)(p2 + (arow + 32) * 128 + c0);
  float4 r1a3 = *(const float4*)(p3 + (arow + 32) * 128 + c0);
  float4 uu = *(const float4*)(Ub + c0);
  float4 b0h = *(const float4*)(BTh + brow * 128 + bslot * 8);
  float4 b1h = *(const float4*)(BTh + (brow + 64) * 128 + bslot * 8);
  float4 b0l = *(const float4*)(BTl + brow * 128 + bslot * 8);
  float4 b1l = *(const float4*)(BTl + (brow + 64) * 128 + bslot * 8);
  floatx4 zero = {0.f, 0.f, 0.f, 0.f};
  floatx4 acc[2][2] = {{zero, zero}, {zero, zero}};
  #pragma unroll
  for (int cc = 0; cc < 128; cc += 64) {
    __syncthreads();
    {
      float4 s0, s1;
      s0.x = (r0a0.x + r0a1.x) + (r0a2.x + r0a3.x) + uu.x;
      s0.y = (r0a0.y + r0a1.y) + (r0a2.y + r0a3.y) + uu.y;
      s0.z = (r0a0.z + r0a1.z) + (r0a2.z + r0a3.z) + uu.z;
      s0.w = (r0a0.w + r0a1.w) + (r0a2.w + r0a3.w) + uu.w;
      s1.x = (r1a0.x + r1a1.x) + (r1a2.x + r1a3.x) + uu.x;
      s1.y = (r1a0.y + r1a1.y) + (r1a2.y + r1a3.y) + uu.y;
      s1.z = (r1a0.z + r1a1.z) + (r1a2.z + r1a3.z) + uu.z;
      s1.w = (r1a0.w + r1a1.w) + (r1a2.w + r1a3.w) + uu.w;
      uint2 h, l;
      pack_split(s0, h, l);
      *(uint2*)((char*)sAh + al0) = h; *(uint2*)((char*)sAl + al0) = l;
      pack_split(s1, h, l);
      *(uint2*)((char*)sAh + al1) = h; *(uint2*)((char*)sAl + al1) = l;
    }
    *(float4*)((char*)sBh + bl0) = b0h;
    *(float4*)((char*)sBh + bl1) = b1h;
    *(float4*)((char*)sBl + bl0) = b0l;
    *(float4*)((char*)sBl + bl1) = b1l;
    __syncthreads();
    if (cc == 0) {   // prefetch cc=64 inputs during compute
      int c1 = 64 + acg * 4;
      r0a0 = *(const float4*)(p0 + arow * 128 + c1);
      r0a1 = *(const float4*)(p1 + arow * 128 + c1);
      r0a2 = *(const float4*)(p2 + arow * 128 + c1);
      r0a3 = *(const float4*)(p3 + arow * 128 + c1);
      r1a0 = *(const float4*)(p0 + (arow + 32) * 128 + c1);
      r1a1 = *(const float4*)(p1 + (arow + 32) * 128 + c1);
      r1a2 = *(const float4*)(p2 + (arow + 32) * 128 + c1);
      r1a3 = *(const float4*)(p3 + (arow + 32) * 128 + c1);
      uu   = *(const float4*)(Ub + c1);
      b0h = *(const float4*)(BTh + 64 + brow * 128 + bslot * 8);
      b1h = *(const float4*)(BTh + 64 + (brow + 64) * 128 + bslot * 8);
      b0l = *(const float4*)(BTl + 64 + brow * 128 + bslot * 8);
      b1l = *(const float4*)(BTl + 64 + (brow + 64) * 128 + bslot * 8);
    }
    #pragma unroll
    for (int kc = 0; kc < 64; kc += 32) {
      half8 ah[2], al[2];
      for (int fm = 0; fm < 2; fm++) {
        ah[fm] = fragP128(sAh, wm * 32 + fm * 16 + lr, kc + lg * 8);
        al[fm] = fragP128(sAl, wm * 32 + fm * 16 + lr, kc + lg * 8);
      }
      for (int fn = 0; fn < 2; fn++) {
        half8 bh = fragP128(sBh, wn * 32 + fn * 16 + lr, kc + lg * 8);
        half8 bl = fragP128(sBl, wn * 32 + fn * 16 + lr, kc + lg * 8);
        for (int fm = 0; fm < 2; fm++) {
          acc[fm][fn] = MFMA16(ah[fm], bh, acc[fm][fn]);
          acc[fm][fn] = MFMA16(ah[fm], bl, acc[fm][fn]);
          acc[fm][fn] = MFMA16(al[fm], bh, acc[fm][fn]);
        }
      }
    }
  }
  __syncthreads();
  float* ef = (float*)pool;   // [64][132] padded fp32
  for (int fm = 0; fm < 2; fm++) for (int fn = 0; fn < 2; fn++) {
    int n = wn * 32 + fn * 16 + lr;
    float bs = bias[n];
    for (int jj = 0; jj < 4; jj++) {
      int m = wm * 32 + fm * 16 + lg * 4 + jj;
      ef[m * 132 + n] = acc[fm][fn][jj] + bs;
    }
  }
  __syncthreads();
  for (int idx = tid; idx < 2048; idx += 512) {
    int r = idx >> 5, sl = idx & 31;
    *(float4*)(out + (rowbase + r) * 128 + sl * 4) = *(const float4*)(ef + r * 132 + sl * 4);
  }
}

// ---- U[b][i][c] = (1/512) * sum over disallowed k-blocks of their column sums of v ----
__global__ void k_U(const f16* __restrict__ vT, float* __restrict__ U) {
  int b = blockIdx.x >> 7, c = blockIdx.x & 127;
  int tid = threadIdx.x;
  const f16* r = vT + ((size_t)b * 128 + c) * 8192;
  float s = 0.f;
  const float4* r4 = (const float4*)(r + tid * 32);
  for (int t = 0; t < 4; t++) {
    float4 v = r4[t];
    const f16* a = (const f16*)&v;
    for (int u = 0; u < 8; u++) s += (float)a[u];
  }
  __shared__ float part[256];
  __shared__ float bs[16];
  part[tid] = s;
  __syncthreads();
  if (tid < 16) {
    float t = 0.f;
    for (int u = 0; u < 16; u++) t += part[tid * 16 + u];
    bs[tid] = t;
  }
  __syncthreads();
  if (tid < 16) {
    int i = tid;
    float tot = 0.f;
    for (int j = 0; j < 16; j++) tot += bs[j];
    int j0 = i - 2 < 0 ? 0 : i - 2;
    int j1 = i + 2 > 15 ? 15 : i + 2;
    float win = 0.f;
    for (int j = j0; j <= j1; j++) win += bs[j];
    U[((size_t)b * 16 + i) * 128 + c] = (tot - win) * (1.0f / 512.0f);
  }
}

// ---- pass A: Z[b][i][j][d] = sum_s exp2(RSL2E * (k_d . q_s)) ----
// with register prefetch of the next sc-chunk's Q tile
__global__ __launch_bounds__(512, 4)
void k_passA(const f16* __restrict__ kp, const f16* __restrict__ qp,
             float* __restrict__ Z) {
  int bid = blockIdx.x;
  int wg = (bid & 7) * 80 + (bid >> 3);     // XCD-aware bijective swizzle (640 = 8*80)
  int dchunk = wg & 3; int rest = wg >> 2;
  int slot = rest % 5; int rest2 = rest / 5;
  int i = rest2 & 15; int b = rest2 >> 4;
  int j = i - 2 + slot;
  if (j < 0 || j > 15) return;
  __shared__ f16 sK[16384], sQ[16384];  // 64 KiB -> 2 WG/CU
  int tid = threadIdx.x, wave = tid >> 6, lane = tid & 63, lg = lane >> 4, lr = lane & 15;
  int wm = wave >> 1, wn = wave & 1;   // 4 x 2 waves; wave tile 32(d) x 64(s)
  size_t krow = (size_t)b * 8192 + j * 512 + dchunk * 128;
  stage_rows128(kp + krow * 128, 128, sK, 128, tid, 512);
  // Q staging duty: rows qr, qr+32, qr+64, qr+96; 16B slot qsl
  int qr = tid >> 4, qsl = tid & 15;
  int ql0 = ((qr << 8) + (qsl << 4)) ^ ((qr & 7) << 4);
  int ql1 = (((qr + 32) << 8) + (qsl << 4)) ^ ((qr & 7) << 4);
  int ql2 = (((qr + 64) << 8) + (qsl << 4)) ^ ((qr & 7) << 4);
  int ql3 = (((qr + 96) << 8) + (qsl << 4)) ^ ((qr & 7) << 4);
  const f16* qb = qp + ((size_t)b * 8192 + i * 512) * 128;
  // prefetch sc=0 Q tile
  float4 q0 = *(const float4*)(qb + (size_t)(qr      ) * 128 + qsl * 8);
  float4 q1 = *(const float4*)(qb + (size_t)(qr +  32) * 128 + qsl * 8);
  float4 q2 = *(const float4*)(qb + (size_t)(qr +  64) * 128 + qsl * 8);
  float4 q3 = *(const float4*)(qb + (size_t)(qr +  96) * 128 + qsl * 8);
  float zp[2][4] = {{0.f,0.f,0.f,0.f},{0.f,0.f,0.f,0.f}};
  floatx4 zero = {0.f, 0.f, 0.f, 0.f};
  for (int sc = 0; sc < 4; sc++) {
    __syncthreads();                 // prev GEMM reads of sQ done (sc=0: K staged)
    *(float4*)((char*)sQ + ql0) = q0;
    *(float4*)((char*)sQ + ql1) = q1;
    *(float4*)((char*)sQ + ql2) = q2;
    *(float4*)((char*)sQ + ql3) = q3;
    __syncthreads();
    if (sc < 3) {                    // prefetch next chunk during compute
      const f16* qn = qb + (size_t)(sc + 1) * 128 * 128;
      q0 = *(const float4*)(qn + (size_t)(qr      ) * 128 + qsl * 8);
      q1 = *(const float4*)(qn + (size_t)(qr +  32) * 128 + qsl * 8);
      q2 = *(const float4*)(qn + (size_t)(qr +  64) * 128 + qsl * 8);
      q3 = *(const float4*)(qn + (size_t)(qr +  96) * 128 + qsl * 8);
    }
    floatx4 acc[2][4] = {{zero,zero,zero,zero},{zero,zero,zero,zero}};
    for (int kc = 0; kc < 128; kc += 32) {
      half8 ah[2];
      for (int fm = 0; fm < 2; fm++)
        ah[fm] = fragP256(sK, wm * 32 + fm * 16 + lr, kc + lg * 8);
      for (int fn = 0; fn < 4; fn++) {
        half8 bh = fragP256(sQ, wn * 64 + fn * 16 + lr, kc + lg * 8);
        for (int fm = 0; fm < 2; fm++)
          acc[fm][fn] = MFMA16(ah[fm], bh, acc[fm][fn]);
      }
    }
    for (int fm = 0; fm < 2; fm++) for (int fn = 0; fn < 4; fn++)
      for (int jj = 0; jj < 4; jj++)
        zp[fm][jj] += exp2f(acc[fm][fn][jj] * RSL2E);
  }
  // in-wave butterfly over lr (16 s-columns)
  for (int off = 1; off < 16; off <<= 1)
    for (int fm = 0; fm < 2; fm++) for (int jj = 0; jj < 4; jj++)
      zp[fm][jj] += __shfl_xor(zp[fm][jj], off, 64);
  // cross-wave combine of the two wn halves via LDS
  __syncthreads();
  float* sred = (float*)sQ;      // 256 floats
  if (lr == 0) {
    for (int fm = 0; fm < 2; fm++) for (int jj = 0; jj < 4; jj++) {
      int d = wm * 32 + fm * 16 + lg * 4 + jj;
      sred[wn * 128 + d] = zp[fm][jj];
    }
  }
  __syncthreads();
  if (tid < 128) {
    size_t zb = (((size_t)(b * 16 + i) * 16 + j) * 512) + dchunk * 128;
    Z[zb + tid] = sred[tid] + sred[128 + tid];
  }
}

// ---- pass B v4 (R12, unchanged): full-width tiles, 4 barriers/iter ----
__global__ __launch_bounds__(512, 4)
void k_passB(const f16* __restrict__ qp, const f16* __restrict__ kp,
             const f16* __restrict__ vT,
             const float* __restrict__ Z, float* __restrict__ Pbuf) {
  int bid = blockIdx.x;
  int wg = ((bid & 7) << 7) | (bid >> 3);   // XCD-aware bijective swizzle (1024 = 8*128)
  int dq = wg & 3, st = (wg >> 2) & 7, i = (wg >> 5) & 15, b = wg >> 9;
  __shared__ __align__(16) char pool[65536];
  f16* sQ  = (f16*)pool;              // [64 s][128 c], 256B pitch, 16 KB
  f16* sKV = (f16*)(pool + 16384);    // [128][128], 256B pitch, 32 KB: K tile, then V tile
  f16* sE  = (f16*)(pool + 49152);    // [64 s][128 d], 256B pitch, 16 KB
  int tid = threadIdx.x, wave = tid >> 6, lane = tid & 63, lg = lane >> 4, lr = lane & 15;
  int w1m = wave >> 1, w1n = wave & 1;    // GEMM1: 4(d) x 2(s)
  int w2m = wave >> 2, w2n = wave & 3;    // GEMM2: 2(s) x 4(c)
  int srow = tid >> 4, sslot = tid & 15;
  int sl0 = (((srow      ) << 8) + (sslot << 4)) ^ ((srow & 7) << 4);
  int sl1 = (((srow +  32) << 8) + (sslot << 4)) ^ ((srow & 7) << 4);
  int sl2 = (((srow +  64) << 8) + (sslot << 4)) ^ ((srow & 7) << 4);
  int sl3 = (((srow +  96) << 8) + (sslot << 4)) ^ ((srow & 7) << 4);
  size_t qrow = (size_t)b * 8192 + i * 512 + st * 64;
  stage_rows128(qp + qrow * 128, 128, sQ, 64, tid, 512);
  floatx4 zero = {0.f, 0.f, 0.f, 0.f};
  floatx4 acc2[2][2] = {{zero, zero}, {zero, zero}};
  const f16* vbase = vT + (size_t)b * 1048576;
  for (int slot = 0; slot < 5; slot++) {
    int j = i - 2 + slot;
    if (j < 0 || j > 15) continue;
    const f16* kb = kp + ((size_t)b * 8192 + j * 512 + dq * 128) * 128;
    float4 k0 = *(const float4*)(kb + (size_t)(srow      ) * 128 + sslot * 8);
    float4 k1 = *(const float4*)(kb + (size_t)(srow +  32) * 128 + sslot * 8);
    float4 k2 = *(const float4*)(kb + (size_t)(srow +  64) * 128 + sslot * 8);
    float4 k3 = *(const float4*)(kb + (size_t)(srow +  96) * 128 + sslot * 8);
    const f16* gv = vbase + (size_t)j * 512 + dq * 128;
    float4 v0 = *(const float4*)(gv + (size_t)(srow      ) * 8192 + sslot * 8);
    float4 v1 = *(const float4*)(gv + (size_t)(srow +  32) * 8192 + sslot * 8);
    float4 v2 = *(const float4*)(gv + (size_t)(srow +  64) * 8192 + sslot * 8);
    float4 v3 = *(const float4*)(gv + (size_t)(srow +  96) * 8192 + sslot * 8);
    float rz[2][4];
    {
      size_t zb = (((size_t)(b * 16 + i) * 16 + j) * 512) + dq * 128;
      #pragma unroll
      for (int fm = 0; fm < 2; fm++)
        #pragma unroll
        for (int jj = 0; jj < 4; jj++)
          rz[fm][jj] = 1.0f / Z[zb + w1m * 32 + fm * 16 + lg * 4 + jj];
    }
    __syncthreads();                 // B1: prev GEMM2 done reading sKV(V)/sE
    *(float4*)((char*)sKV + sl0) = k0;
    *(float4*)((char*)sKV + sl1) = k1;
    *(float4*)((char*)sKV + sl2) = k2;
    *(float4*)((char*)sKV + sl3) = k3;
    __syncthreads();                 // B2: K tile staged
    floatx4 acc1[2][2] = {{zero, zero}, {zero, zero}};
    #pragma unroll
    for (int kc = 0; kc < 128; kc += 32) {
      half8 ah0 = fragP256(sKV, w1m * 32 + lr, kc + lg * 8);
      half8 ah1 = fragP256(sKV, w1m * 32 + 16 + lr, kc + lg * 8);
      #pragma unroll
      for (int fn = 0; fn < 2; fn++) {
        half8 bq = fragP256(sQ, w1n * 32 + fn * 16 + lr, kc + lg * 8);
        acc1[0][fn] = MFMA16(ah0, bq, acc1[0][fn]);
        acc1[1][fn] = MFMA16(ah1, bq, acc1[1][fn]);
      }
    }
    __syncthreads();                 // B3: GEMM1 reads of sKV done
    #pragma unroll
    for (int fm = 0; fm < 2; fm++)
      #pragma unroll
      for (int fn = 0; fn < 2; fn++) {
        int s = w1n * 32 + fn * 16 + lr;
        int d0 = w1m * 32 + fm * 16 + lg * 4;
        union { f16 a[4]; float2 u; } pk;
        #pragma unroll
        for (int jj = 0; jj < 4; jj++)
          pk.a[jj] = (f16)(exp2f(acc1[fm][fn][jj] * RSL2E) * rz[fm][jj]);
        int ofs = ((s << 8) + (d0 << 1)) ^ ((s & 7) << 4);
        *(float2*)((char*)sE + ofs) = pk.u;
      }
    *(float4*)((char*)sKV + sl0) = v0;
    *(float4*)((char*)sKV + sl1) = v1;
    *(float4*)((char*)sKV + sl2) = v2;
    *(float4*)((char*)sKV + sl3) = v3;
    __syncthreads();                 // B4: E + V staged
    #pragma unroll
    for (int kc = 0; kc < 128; kc += 32) {
      half8 ea0 = fragP256(sE, w2m * 32 + lr, kc + lg * 8);
      half8 ea1 = fragP256(sE, w2m * 32 + 16 + lr, kc + lg * 8);
      #pragma unroll
      for (int fn = 0; fn < 2; fn++) {
        half8 bh = fragP256(sKV, w2n * 32 + fn * 16 + lr, kc + lg * 8);
        acc2[0][fn] = MFMA16(ea0, bh, acc2[0][fn]);
        acc2[1][fn] = MFMA16(ea1, bh, acc2[1][fn]);
      }
    }
  }
  __syncthreads();
  float* ef = (float*)pool;   // [64][128] f32 = 32 KB
  for (int fm = 0; fm < 2; fm++) for (int fn = 0; fn < 2; fn++) {
    int c = w2n * 32 + fn * 16 + lr;
    for (int jj = 0; jj < 4; jj++) {
      int s = w2m * 32 + fm * 16 + lg * 4 + jj;
      ef[s * 128 + c] = acc2[fm][fn][jj];
    }
  }
  __syncthreads();
  float* po = Pbuf + ((size_t)((((b * 16 + i) * 8 + st) * 4) + dq)) * 8192;
  for (int idx = tid; idx < 2048; idx += 512)
    ((float4*)po)[idx] = ((const float4*)ef)[idx];
}

extern "C" void kernel_launch(void* const* d_in, const int* in_sizes, int n_in,
                              void* d_out, int out_size, void* d_ws, size_t ws_size,
                              hipStream_t stream) {
  const float* query     = (const float*)d_in[0];
  const float* key_value = (const float*)d_in[1];
  const float* Wq  = (const float*)d_in[2];
  const float* bq  = (const float*)d_in[3];
  const float* Wkv = (const float*)d_in[4];
  const float* bkv = (const float*)d_in[5];
  const float* Wo  = (const float*)d_in[6];
  const float* bo  = (const float*)d_in[7];
  float* out = (float*)d_out;

  char* ws = (char*)d_ws;
  size_t off = 0;
  auto alloc = [&](size_t bytes) -> char* {
    char* p = ws + off;
    off += (bytes + 255) & ~(size_t)255;
    return p;
  };
  const size_t SZH = (size_t)16384 * 128 * 2;   // one f16 array over all rows
  f16* qhp  = (f16*)alloc(SZH);   // q projected, single f16
  f16* khp  = (f16*)alloc(SZH);   // k projected, single f16
  f16* vT   = (f16*)alloc(SZH);   // v projected, transposed [b][c][l], single f16
  float* Pbuf = (float*)alloc((size_t)1024 * 8192 * 4);   // 33.5 MB partials (4 d-quarters)
  f16* WqTh  = (f16*)alloc(32768); f16* WqTl  = (f16*)alloc(32768);
  f16* WkvTh = (f16*)alloc(65536); f16* WkvTl = (f16*)alloc(65536);
  f16* WoTh  = (f16*)alloc(32768); f16* WoTl  = (f16*)alloc(32768);
  float* Zb = (float*)alloc((size_t)2 * 16 * 16 * 512 * 4);
  float* Ub = (float*)alloc((size_t)2 * 16 * 128 * 4);
  if (off > ws_size) return;   // workspace too small: bail

  k_splitW<<<256, 256, 0, stream>>>(Wq, Wkv, Wo, WqTh, WqTl, WkvTh, WkvTl, WoTh, WoTl);
  k_proj<<<768, 512, 0, stream>>>(query, key_value, WqTh, WqTl, WkvTh, WkvTl,
                                  bq, bkv, qhp, khp, vT);
  k_U<<<256, 256, 0, stream>>>(vT, Ub);
  k_passA<<<640, 512, 0, stream>>>(khp, qhp, Zb);
  k_passB<<<1024, 512, 0, stream>>>(qhp, khp, vT, Zb, Pbuf);
  k_final<<<256, 512, 0, stream>>>(Pbuf, Ub, WoTh, WoTl, bo, out);
}